// Round 3
// baseline (162.282 us; speedup 1.0000x reference)
//
#include <hip/hip_runtime.h>
#include <hip/hip_bf16.h>
#include <stdint.h>

// B=8, N=1024, D=512, H=8, DK=64, ALPHA=0.2
//
// Scratch plan (robust to small ws_size):
//   ws  : xb (attention output, bf16 [8192][512]) @ 0, 8,388,608 bytes.
//   d_out (16,777,216 bytes f32) doubles as scratch; all regions are
//   write-before-read within one call and dead before gemm<0> overwrites:
//     vt   @ 0          8,388,608  (v^T per head: [b][h][dk][n] bf16)
//     mbit @ 8,388,608  1,048,576  (mask bitset, [b][i][128B])
//     sq   @ 9,437,184    262,144  ([b][h][n] f32, pre-scaled by log2e)
//     sk   @ 9,699,328    262,144  (pre-scaled by log2e)
//     Aq   @ 9,961,472     16,384  ([d][h] f32)
//     Ak   @ 9,977,856     16,384
//     qb   @ 9,994,240        256
//     kb   @ 9,994,496        256

typedef __attribute__((ext_vector_type(8))) short short8;
typedef __attribute__((ext_vector_type(4))) float f32x4;

#define LB __launch_bounds__(256)

__device__ __forceinline__ unsigned short f2bf(float f) {
  unsigned int u = __float_as_uint(f);
  u += 0x7fffu + ((u >> 16) & 1u);
  return (unsigned short)(u >> 16);
}

__device__ __forceinline__ short f2bf_native(float f) {
  union { __hip_bfloat16 h; unsigned short u; } cv;
  cv.h = __float2bfloat16(f);
  return (short)cv.u;
}

// ---------------- fold attention vector a into Wq/Wk ----------------
__global__ LB void prep_a_kernel(const float* __restrict__ Wq, const float* __restrict__ Wk,
                                 const float* __restrict__ a, const float* __restrict__ bq,
                                 const float* __restrict__ bk,
                                 float* __restrict__ Aq, float* __restrict__ Ak,
                                 float* __restrict__ qb, float* __restrict__ kb) {
  const int t = blockIdx.x * 256 + threadIdx.x;  // 4096 threads: (d,h)
  const int h = t & 7, d = t >> 3;
  float aq = 0.f, ak = 0.f;
  for (int dk = 0; dk < 64; ++dk) {
    aq += Wq[(size_t)(h * 64 + dk) * 512 + d] * a[h * 128 + dk];
    ak += Wk[(size_t)(h * 64 + dk) * 512 + d] * a[h * 128 + 64 + dk];
  }
  Aq[d * 8 + h] = aq;
  Ak[d * 8 + h] = ak;
  if (d == 0) {
    float s1 = 0.f, s2 = 0.f;
    for (int dk = 0; dk < 64; ++dk) {
      s1 += bq[h * 64 + dk] * a[h * 128 + dk];
      s2 += bk[h * 64 + dk] * a[h * 128 + 64 + dk];
    }
    qb[h] = s1;
    kb[h] = s2;
  }
}

// ---------------- sq/sk: rank-8 projections, pre-scaled by log2(e) ----------------
__global__ LB void sqsk_kernel(const float* __restrict__ query, const float* __restrict__ key,
                               const float* __restrict__ Aq, const float* __restrict__ Ak,
                               const float* __restrict__ qb, const float* __restrict__ kb,
                               float* __restrict__ sq, float* __restrict__ sk) {
  const int t = blockIdx.x * 256 + threadIdx.x;  // 65536 threads: (row, h)
  const int h = t & 7, r = t >> 3;
  const float* qrow = query + (size_t)r * 512;
  const float* krow = key + (size_t)r * 512;
  float aq = 0.f, ak = 0.f;
  for (int d = 0; d < 512; d += 4) {
    const float4 qv = *(const float4*)(qrow + d);
    const float4 kv = *(const float4*)(krow + d);
    aq += qv.x * Aq[(d + 0) * 8 + h] + qv.y * Aq[(d + 1) * 8 + h]
        + qv.z * Aq[(d + 2) * 8 + h] + qv.w * Aq[(d + 3) * 8 + h];
    ak += kv.x * Ak[(d + 0) * 8 + h] + kv.y * Ak[(d + 1) * 8 + h]
        + kv.z * Ak[(d + 2) * 8 + h] + kv.w * Ak[(d + 3) * 8 + h];
  }
  const int b = r >> 10, n = r & 1023;
  const float L2E = 1.44269504088896f;
  sq[((size_t)b * 8 + h) * 1024 + n] = (aq + qb[h]) * L2E;
  sk[((size_t)b * 8 + h) * 1024 + n] = (ak + kb[h]) * L2E;
}

// ---------------- mask (B,N,N) int32 -> bitset ----------------
__global__ LB void maskbits_kernel(const int* __restrict__ mask,
                                   unsigned int* __restrict__ bits) {
  const size_t idx = (size_t)blockIdx.x * 256 + threadIdx.x;
  const unsigned long long bl = __ballot(mask[idx] != 0);
  if ((threadIdx.x & 63) == 0) {
    bits[idx >> 5] = (unsigned int)bl;
    bits[(idx >> 5) + 1] = (unsigned int)(bl >> 32);
  }
}

// ---------------- bf16 MFMA GEMM: C[8192][512] = A @ Bw[512][512]^T + bias
// AF32: A is fp32 (cast to bf16 during staging); else A is bf16.
// MODE 0: C -> fp32 row-major.  MODE 1: C -> bf16 v^T layout [b][h][dk][n].
template <int AF32, int MODE>
__global__ LB void gemm_bt(const void* __restrict__ Ap,
                           const float* __restrict__ Bw,
                           const float* __restrict__ bias, void* __restrict__ outp) {
  __shared__ unsigned short As[128 * 32];
  __shared__ unsigned short Bs[128 * 32];
  const int tid = threadIdx.x;
  const int w = tid >> 6, l = tid & 63;
  const int lr = l & 15, lc = l >> 4;
  const int bm = blockIdx.x >> 2, bn = blockIdx.x & 3;  // grid 256: 64 x 4
  const int m0 = bm * 128, n0 = bn * 128;
  const int wr = (w >> 1) * 64, wc = (w & 1) * 64;
  f32x4 acc[4][4] = {};
  for (int kt = 0; kt < 16; ++kt) {
    const int k0 = kt * 32;
    if (kt) __syncthreads();
#pragma unroll
    for (int it = 0; it < 2; ++it) {
      int idx = it * 256 + tid;  // 0..511
      int row = idx >> 2, gr = idx & 3;
      if (AF32) {
        const float4* src = (const float4*)((const float*)Ap + (size_t)(m0 + row) * 512 + k0 + gr * 8);
        const float4 a0 = src[0], a1 = src[1];
        unsigned short t8[8] = {f2bf(a0.x), f2bf(a0.y), f2bf(a0.z), f2bf(a0.w),
                                f2bf(a1.x), f2bf(a1.y), f2bf(a1.z), f2bf(a1.w)};
        *(short8*)(As + row * 32 + gr * 8) = *(short8*)t8;
      } else {
        *(short8*)(As + row * 32 + gr * 8) =
            *(const short8*)((const unsigned short*)Ap + (size_t)(m0 + row) * 512 + k0 + gr * 8);
      }
      {
        const float4* src = (const float4*)(Bw + (size_t)(n0 + row) * 512 + k0 + gr * 8);
        const float4 b0 = src[0], b1 = src[1];
        unsigned short t8[8] = {f2bf(b0.x), f2bf(b0.y), f2bf(b0.z), f2bf(b0.w),
                                f2bf(b1.x), f2bf(b1.y), f2bf(b1.z), f2bf(b1.w)};
        *(short8*)(Bs + row * 32 + gr * 8) = *(short8*)t8;
      }
    }
    __syncthreads();
    short8 af[4], bfr[4];
#pragma unroll
    for (int g = 0; g < 4; ++g) {
      af[g]  = *(const short8*)(As + (wr + g * 16 + lr) * 32 + lc * 8);
      bfr[g] = *(const short8*)(Bs + (wc + g * 16 + lr) * 32 + lc * 8);
    }
#pragma unroll
    for (int i = 0; i < 4; ++i)
#pragma unroll
      for (int j = 0; j < 4; ++j)
        acc[i][j] = __builtin_amdgcn_mfma_f32_16x16x32_bf16(af[i], bfr[j], acc[i][j], 0, 0, 0);
  }
#pragma unroll
  for (int i = 0; i < 4; ++i) {
#pragma unroll
    for (int j = 0; j < 4; ++j) {
      const int nn = n0 + wc + j * 16 + lr;
      const float bia = bias[nn];
      if (MODE == 0) {
        float* out = (float*)outp;
#pragma unroll
        for (int r = 0; r < 4; ++r) {
          const int mm = m0 + wr + i * 16 + lc * 4 + r;
          out[(size_t)mm * 512 + nn] = acc[i][j][r] + bia;
        }
      } else {
        unsigned short* out = (unsigned short*)outp;
        const int mm0 = m0 + wr + i * 16 + lc * 4;
        const int b = mm0 >> 10, t0 = mm0 & 1023;
        const int h = nn >> 6, dk = nn & 63;
        unsigned long long pk = 0;
#pragma unroll
        for (int r = 0; r < 4; ++r)
          pk |= (unsigned long long)f2bf(acc[i][j][r] + bia) << (16 * r);
        *(unsigned long long*)(out + (((size_t)((b * 8 + h) * 64 + dk)) << 10) + t0) = pk;
      }
    }
  }
}

// ---------------- fused attention, j-split 4x within block ----------------
// Block = 4 waves over 32 i-rows of one (b,h); wave w covers j in [256w,256w+256).
// Partial acc/accs combined through LDS, wave 0 normalizes and writes.
// sq/sk arrive pre-scaled by log2(e): w = exp2(lrelu(sq_i+sk_j)) * maskbit.
__global__ LB void attn_kernel(const float* __restrict__ sq, const float* __restrict__ sk,
                               const unsigned char* __restrict__ mbits,
                               const unsigned short* __restrict__ vt,
                               unsigned short* __restrict__ xb) {
  __shared__ float buf[2][64 * 41];
  const int tid = threadIdx.x;
  const int w = tid >> 6, l = tid & 63;
  const int lr = l & 15, lc = l >> 4;
  const int bid = blockIdx.x;  // 2048 blocks: b(8) x h(8) x iq(32)
  const int b = bid >> 8, h = (bid >> 5) & 7, iq = bid & 31;
  const int i0 = iq * 32;
  const int bh = b * 8 + h;
  const float* sqp = sq + (size_t)bh * 1024;
  const float* skp = sk + (size_t)bh * 1024;
  const unsigned short* vtp = vt + ((size_t)bh << 16);
  const unsigned char* mrow = mbits + ((size_t)b << 17);
  float sq2[2];
#pragma unroll
  for (int g = 0; g < 2; ++g) sq2[g] = sqp[i0 + g * 16 + lr];
  f32x4 acc[2][4] = {};
  f32x4 accs[2] = {};
  short8 ones;
#pragma unroll
  for (int t = 0; t < 8; ++t) ones[t] = (short)0x3f80;  // bf16 1.0
  const int j0 = w * 256;
  for (int jt = 0; jt < 8; ++jt) {
    const int jb = j0 + jt * 32;
    const float4* skv4 = (const float4*)(skp + jb + lc * 8);
    const float4 s0 = skv4[0], s1 = skv4[1];
    const float skl[8] = {s0.x, s0.y, s0.z, s0.w, s1.x, s1.y, s1.z, s1.w};
    short8 pa[2];
#pragma unroll
    for (int g = 0; g < 2; ++g) {
      const int i = i0 + g * 16 + lr;
      const unsigned int mb = mrow[((size_t)i << 7) + (jb >> 3) + lc];
      const float sqv = sq2[g];
#pragma unroll
      for (int t = 0; t < 8; ++t) {
        float s = sqv + skl[t];
        s = fmaxf(s, 0.2f * s);                       // leaky relu (scale-invariant)
        const float wv = ((mb >> t) & 1u) ? __builtin_amdgcn_exp2f(s) : 0.0f;
        pa[g][t] = f2bf_native(wv);
      }
    }
#pragma unroll
    for (int c = 0; c < 4; ++c) {
      const short8 bv = *(const short8*)(vtp + (((size_t)(c * 16 + lr)) << 10) + jb + lc * 8);
#pragma unroll
      for (int g = 0; g < 2; ++g)
        acc[g][c] = __builtin_amdgcn_mfma_f32_16x16x32_bf16(pa[g], bv, acc[g][c], 0, 0, 0);
    }
#pragma unroll
    for (int g = 0; g < 2; ++g)
      accs[g] = __builtin_amdgcn_mfma_f32_16x16x32_bf16(pa[g], ones, accs[g], 0, 0, 0);
  }

  // ---- cross-wave combine: (w1 -> buf0 <- w0) || (w3 -> buf1 <- w2); then w2 -> buf0 <- w0
#define STORE_P(B)                                                             \
  {                                                                            \
    float* p = &buf[B][l * 41];                                                \
    _Pragma("unroll") for (int g = 0; g < 2; ++g)                              \
    _Pragma("unroll") for (int c = 0; c < 4; ++c)                              \
    _Pragma("unroll") for (int r = 0; r < 4; ++r)                              \
        p[(g * 4 + c) * 4 + r] = acc[g][c][r];                                 \
    _Pragma("unroll") for (int g = 0; g < 2; ++g)                              \
    _Pragma("unroll") for (int r = 0; r < 4; ++r) p[32 + g * 4 + r] = accs[g][r]; \
  }
#define ADD_P(B)                                                               \
  {                                                                            \
    const float* p = &buf[B][l * 41];                                          \
    _Pragma("unroll") for (int g = 0; g < 2; ++g)                              \
    _Pragma("unroll") for (int c = 0; c < 4; ++c)                              \
    _Pragma("unroll") for (int r = 0; r < 4; ++r)                              \
        acc[g][c][r] += p[(g * 4 + c) * 4 + r];                                \
    _Pragma("unroll") for (int g = 0; g < 2; ++g)                              \
    _Pragma("unroll") for (int r = 0; r < 4; ++r) accs[g][r] += p[32 + g * 4 + r]; \
  }
  if (w == 1) STORE_P(0);
  if (w == 3) STORE_P(1);
  __syncthreads();
  if (w == 0) ADD_P(0);
  if (w == 2) ADD_P(1);
  __syncthreads();
  if (w == 2) STORE_P(0);
  __syncthreads();
  if (w == 0) {
    ADD_P(0);
#pragma unroll
    for (int g = 0; g < 2; ++g) {
#pragma unroll
      for (int r = 0; r < 4; ++r) {
        const float s = accs[g][r];
        const float inv = s > 0.0f ? 1.0f / s : 0.0f;  // fully-masked row -> 0
        const int i = i0 + g * 16 + lc * 4 + r;
#pragma unroll
        for (int c = 0; c < 4; ++c)
          xb[(((size_t)(b * 1024 + i)) << 9) + h * 64 + c * 16 + lr] =
              f2bf(acc[g][c][r] * inv);
      }
    }
  }
#undef STORE_P
#undef ADD_P
}

extern "C" void kernel_launch(void* const* d_in, const int* in_sizes, int n_in,
                              void* d_out, int out_size, void* d_ws, size_t ws_size,
                              hipStream_t stream) {
  const float* query = (const float*)d_in[0];
  const float* key   = (const float*)d_in[1];
  const float* value = (const float*)d_in[2];
  const int*   mask  = (const int*)d_in[3];
  const float* Wq = (const float*)d_in[4];
  const float* bq = (const float*)d_in[5];
  const float* Wk = (const float*)d_in[6];
  const float* bk = (const float*)d_in[7];
  const float* Wv = (const float*)d_in[8];
  const float* bv = (const float*)d_in[9];
  const float* Wo = (const float*)d_in[10];
  const float* bo = (const float*)d_in[11];
  const float* a  = (const float*)d_in[12];

  // d_out doubles as scratch (fully overwritten by the final GEMM).
  char* oc = (char*)d_out;
  unsigned short* vt = (unsigned short*)(oc + 0);
  unsigned int* mbits = (unsigned int*)(oc + 8388608);
  float* sqv = (float*)(oc + 9437184);
  float* skv = (float*)(oc + 9699328);
  float* Aq  = (float*)(oc + 9961472);
  float* Ak  = (float*)(oc + 9977856);
  float* qbf = (float*)(oc + 9994240);
  float* kbf = (float*)(oc + 9994496);
  // ws: only the attention output (must not alias d_out during final GEMM).
  unsigned short* xb = (unsigned short*)d_ws;  // 8,388,608 bytes

  prep_a_kernel<<<16, 256, 0, stream>>>(Wq, Wk, a, bq, bk, Aq, Ak, qbf, kbf);
  sqsk_kernel<<<256, 256, 0, stream>>>(query, key, Aq, Ak, qbf, kbf, sqv, skv);
  maskbits_kernel<<<32768, 256, 0, stream>>>(mask, mbits);
  gemm_bt<1, 1><<<256, 256, 0, stream>>>((const void*)value, Wv, bv, (void*)vt);
  attn_kernel<<<2048, 256, 0, stream>>>(sqv, skv, (const unsigned char*)mbits, vt, xb);
  gemm_bt<0, 0><<<256, 256, 0, stream>>>((const void*)xb, Wo, bo, d_out);
}

// Round 4
// 138.004 us; speedup vs baseline: 1.1759x; 1.1759x over previous
//
#include <hip/hip_runtime.h>
#include <hip/hip_bf16.h>
#include <stdint.h>

// B=8, N=1024, D=512, H=8, DK=64, ALPHA=0.2
//
// Scratch plan:
//   ws  : xb (attention output, bf16 [8192][512]) @ 0, 8,388,608 bytes.
//   d_out (16,777,216 bytes f32) doubles as scratch; all regions are
//   write-before-read within one call and dead before gemm<0> overwrites:
//     vt   @ 0          8,388,608  (v^T per head: [b][h][dk][n] bf16)
//     mbit @ 8,388,608  1,048,576  (mask bitset, [b][i][128B])
//     sq   @ 9,437,184    262,144  ([b][h][n] f32, pre-scaled by log2e)
//     sk   @ 9,699,328    262,144  (pre-scaled by log2e)
//     Aq   @ 9,961,472     16,384  ([d][h] f32)
//     Ak   @ 9,977,856     16,384
//     qb   @ 9,994,240        256
//     kb   @ 9,994,496        256

typedef __attribute__((ext_vector_type(8))) short short8;
typedef __attribute__((ext_vector_type(4))) float f32x4;

#define LB __launch_bounds__(256)

__device__ __forceinline__ unsigned short f2bf(float f) {
  unsigned int u = __float_as_uint(f);
  u += 0x7fffu + ((u >> 16) & 1u);
  return (unsigned short)(u >> 16);
}

__device__ __forceinline__ short f2bf_native(float f) {
  union { __hip_bfloat16 h; unsigned short u; } cv;
  cv.h = __float2bfloat16(f);
  return (short)cv.u;
}

// async global->LDS, 16B per lane. lptr = wave-uniform base; gptr = per-lane.
__device__ __forceinline__ void async_cp16(const void* g, void* l) {
  __builtin_amdgcn_global_load_lds(
      (const __attribute__((address_space(1))) unsigned int*)g,
      (__attribute__((address_space(3))) unsigned int*)l, 16, 0, 0);
}

// ---------------- fold attention vector a into Wq/Wk ----------------
__global__ LB void prep_a_kernel(const float* __restrict__ Wq, const float* __restrict__ Wk,
                                 const float* __restrict__ a, const float* __restrict__ bq,
                                 const float* __restrict__ bk,
                                 float* __restrict__ Aq, float* __restrict__ Ak,
                                 float* __restrict__ qb, float* __restrict__ kb) {
  const int t = blockIdx.x * 256 + threadIdx.x;  // 4096 threads: d fast (coalesced), h slow
  const int d = t & 511, h = t >> 9;
  float aq = 0.f, ak = 0.f;
  for (int dk = 0; dk < 64; ++dk) {
    aq += Wq[(size_t)(h * 64 + dk) * 512 + d] * a[h * 128 + dk];
    ak += Wk[(size_t)(h * 64 + dk) * 512 + d] * a[h * 128 + 64 + dk];
  }
  Aq[d * 8 + h] = aq;
  Ak[d * 8 + h] = ak;
  if (d == 0) {
    float s1 = 0.f, s2 = 0.f;
    for (int dk = 0; dk < 64; ++dk) {
      s1 += bq[h * 64 + dk] * a[h * 128 + dk];
      s2 += bk[h * 64 + dk] * a[h * 128 + 64 + dk];
    }
    qb[h] = s1;
    kb[h] = s2;
  }
}

// ---------------- sq/sk: rank-8 projections, pre-scaled by log2(e) ----------------
__global__ LB void sqsk_kernel(const float* __restrict__ query, const float* __restrict__ key,
                               const float* __restrict__ Aq, const float* __restrict__ Ak,
                               const float* __restrict__ qb, const float* __restrict__ kb,
                               float* __restrict__ sq, float* __restrict__ sk) {
  const int t = blockIdx.x * 256 + threadIdx.x;  // 65536 threads: (row, h)
  const int h = t & 7, r = t >> 3;
  const float* qrow = query + (size_t)r * 512;
  const float* krow = key + (size_t)r * 512;
  float aq = 0.f, ak = 0.f;
  for (int d = 0; d < 512; d += 4) {
    const float4 qv = *(const float4*)(qrow + d);
    const float4 kv = *(const float4*)(krow + d);
    aq += qv.x * Aq[(d + 0) * 8 + h] + qv.y * Aq[(d + 1) * 8 + h]
        + qv.z * Aq[(d + 2) * 8 + h] + qv.w * Aq[(d + 3) * 8 + h];
    ak += kv.x * Ak[(d + 0) * 8 + h] + kv.y * Ak[(d + 1) * 8 + h]
        + kv.z * Ak[(d + 2) * 8 + h] + kv.w * Ak[(d + 3) * 8 + h];
  }
  const int b = r >> 10, n = r & 1023;
  const float L2E = 1.44269504088896f;
  sq[((size_t)b * 8 + h) * 1024 + n] = (aq + qb[h]) * L2E;
  sk[((size_t)b * 8 + h) * 1024 + n] = (ak + kb[h]) * L2E;
}

// ---------------- mask (B,N,N) int32 -> bitset ----------------
__global__ LB void maskbits_kernel(const int* __restrict__ mask,
                                   unsigned int* __restrict__ bits) {
  const size_t idx = (size_t)blockIdx.x * 256 + threadIdx.x;
  const unsigned long long bl = __ballot(mask[idx] != 0);
  if ((threadIdx.x & 63) == 0) {
    bits[idx >> 5] = (unsigned int)bl;
    bits[(idx >> 5) + 1] = (unsigned int)(bl >> 32);
  }
}

// ---------------- bf16 MFMA GEMM: C[8192][512] = A @ Bw[512][512]^T + bias
// AF32: A is fp32 (cast to bf16 during staging); else A is bf16.
// MODE 0: C -> fp32 row-major.  MODE 1: C -> bf16 v^T layout [b][h][dk][n].
template <int AF32, int MODE>
__global__ LB void gemm_bt(const void* __restrict__ Ap,
                           const float* __restrict__ Bw,
                           const float* __restrict__ bias, void* __restrict__ outp) {
  __shared__ unsigned short As[128 * 32];
  __shared__ unsigned short Bs[128 * 32];
  const int tid = threadIdx.x;
  const int w = tid >> 6, l = tid & 63;
  const int lr = l & 15, lc = l >> 4;
  const int bm = blockIdx.x >> 2, bn = blockIdx.x & 3;  // grid 256: 64 x 4
  const int m0 = bm * 128, n0 = bn * 128;
  const int wr = (w >> 1) * 64, wc = (w & 1) * 64;
  f32x4 acc[4][4] = {};
  for (int kt = 0; kt < 16; ++kt) {
    const int k0 = kt * 32;
    if (kt) __syncthreads();
#pragma unroll
    for (int it = 0; it < 2; ++it) {
      int idx = it * 256 + tid;  // 0..511
      int row = idx >> 2, gr = idx & 3;
      if (AF32) {
        const float4* src = (const float4*)((const float*)Ap + (size_t)(m0 + row) * 512 + k0 + gr * 8);
        const float4 a0 = src[0], a1 = src[1];
        unsigned short t8[8] = {f2bf(a0.x), f2bf(a0.y), f2bf(a0.z), f2bf(a0.w),
                                f2bf(a1.x), f2bf(a1.y), f2bf(a1.z), f2bf(a1.w)};
        *(short8*)(As + row * 32 + gr * 8) = *(short8*)t8;
      } else {
        *(short8*)(As + row * 32 + gr * 8) =
            *(const short8*)((const unsigned short*)Ap + (size_t)(m0 + row) * 512 + k0 + gr * 8);
      }
      {
        const float4* src = (const float4*)(Bw + (size_t)(n0 + row) * 512 + k0 + gr * 8);
        const float4 b0 = src[0], b1 = src[1];
        unsigned short t8[8] = {f2bf(b0.x), f2bf(b0.y), f2bf(b0.z), f2bf(b0.w),
                                f2bf(b1.x), f2bf(b1.y), f2bf(b1.z), f2bf(b1.w)};
        *(short8*)(Bs + row * 32 + gr * 8) = *(short8*)t8;
      }
    }
    __syncthreads();
    short8 af[4], bfr[4];
#pragma unroll
    for (int g = 0; g < 4; ++g) {
      af[g]  = *(const short8*)(As + (wr + g * 16 + lr) * 32 + lc * 8);
      bfr[g] = *(const short8*)(Bs + (wc + g * 16 + lr) * 32 + lc * 8);
    }
#pragma unroll
    for (int i = 0; i < 4; ++i)
#pragma unroll
      for (int j = 0; j < 4; ++j)
        acc[i][j] = __builtin_amdgcn_mfma_f32_16x16x32_bf16(af[i], bfr[j], acc[i][j], 0, 0, 0);
  }
#pragma unroll
  for (int i = 0; i < 4; ++i) {
#pragma unroll
    for (int j = 0; j < 4; ++j) {
      const int nn = n0 + wc + j * 16 + lr;
      const float bia = bias[nn];
      if (MODE == 0) {
        float* out = (float*)outp;
#pragma unroll
        for (int r = 0; r < 4; ++r) {
          const int mm = m0 + wr + i * 16 + lc * 4 + r;
          out[(size_t)mm * 512 + nn] = acc[i][j][r] + bia;
        }
      } else {
        unsigned short* out = (unsigned short*)outp;
        const int mm0 = m0 + wr + i * 16 + lc * 4;
        const int b = mm0 >> 10, t0 = mm0 & 1023;
        const int h = nn >> 6, dk = nn & 63;
        unsigned long long pk = 0;
#pragma unroll
        for (int r = 0; r < 4; ++r)
          pk |= (unsigned long long)f2bf(acc[i][j][r] + bia) << (16 * r);
        *(unsigned long long*)(out + (((size_t)((b * 8 + h) * 64 + dk)) << 10) + t0) = pk;
      }
    }
  }
}

// ---------------- fused attention, LDS-staged, double-buffered vt ----------------
// Block = 4 waves x 16 i-rows = 64 rows of one (b,h); full j per wave (no combine).
// LDS: vt j-slab dbuf (2x4KB, swizzled), sk (4KB), mask slab (8KB, swizzled).
// sq/sk arrive pre-scaled by log2(e): w = exp2(lrelu(sq_i+sk_j)) * maskbit.
__global__ LB void attn_kernel(const float* __restrict__ sq, const float* __restrict__ sk,
                               const unsigned char* __restrict__ mbits,
                               const unsigned short* __restrict__ vt,
                               unsigned short* __restrict__ xb) {
  __shared__ char smem[20480];
  unsigned short* vts = (unsigned short*)smem;  // [2][64dk][32j] bf16, chunk-swizzled
  float* sks = (float*)(smem + 8192);           // [1024] f32
  char* mks = smem + 12288;                     // [64 rows][128B], byte-swizzled
  const int tid = threadIdx.x;
  const int w = tid >> 6, l = tid & 63;
  const int lr = l & 15, lc = l >> 4;
  const int bid = blockIdx.x;  // 1024 blocks: bh(64) x iblk(16); iblk fast for L2 share
  const int bh = bid >> 4, iblk = bid & 15;
  const int b = bh >> 3, h = bh & 7;
  const int i0b = iblk * 64, i0w = i0b + (w << 4);
  const float* sqp = sq + (size_t)bh * 1024;
  const float* skp = sk + (size_t)bh * 1024;
  const unsigned short* vtp = vt + ((size_t)bh << 16);
  const unsigned char* mrow = mbits + ((size_t)b << 17);

  // ---- prologue staging (async, drained by the syncthreads below)
  // sk: wave w covers f32 idx [w*256, w*256+256)
  async_cp16(skp + (w << 8) + l * 4, sks + (w << 8));
  // mask slab: 64 rows x 128B, swizzled store: LDS[row][q] = M[row][q ^ ((row&7)<<4)]
  {
    const int row0 = (w << 4) + (l >> 3);
    const int c0 = (l & 7) ^ (row0 & 7);
    async_cp16(mrow + (size_t)(i0b + row0) * 128 + (c0 << 4), mks + (w << 11));
    const int row1 = row0 + 8;
    const int c1 = (l & 7) ^ (row1 & 7);
    async_cp16(mrow + (size_t)(i0b + row1) * 128 + (c1 << 4), mks + (w << 11) + 1024);
  }
  // vt slab stage: [64 dk][32 j], source-swizzled: chunk' = chunk ^ ((dk>>1)&3)
  const int st_dk = (w << 4) + (l >> 2);
  const int st_ch = (l & 3) ^ ((st_dk >> 1) & 3);
  const unsigned short* st_base = vtp + st_dk * 1024 + st_ch * 8;
  async_cp16(st_base, vts + (w << 9));  // jb = 0 into buf 0

  const float sq1 = sqp[i0w + lr];
  __syncthreads();

  f32x4 acc[4] = {};
  f32x4 accs = {};
  short8 ones;
#pragma unroll
  for (int t = 0; t < 8; ++t) ones[t] = (short)0x3f80;  // bf16 1.0
  const int rowl = (w << 4) + lr;
  const int mrowbase = rowl << 7;
  const int rxor = (rowl & 7) << 4;
  const int vread = ((lc ^ ((lr >> 1) & 3)) << 3);

  int cur = 0;
  for (int jt = 0; jt < 32; ++jt) {
    const int jb = jt * 32;
    if (jt < 31)  // stage next slab into the other buffer
      async_cp16(st_base + jb + 32, vts + ((cur ^ 1) << 11) + (w << 9));
    // scores for this wave's 16 rows x 32 j
    const unsigned int mb = (unsigned char)mks[mrowbase + ((jt * 4 + lc) ^ rxor)];
    const f32x4 s0 = *(const f32x4*)(sks + jb + lc * 8);
    const f32x4 s1 = *(const f32x4*)(sks + jb + lc * 8 + 4);
    const float skl[8] = {s0[0], s0[1], s0[2], s0[3], s1[0], s1[1], s1[2], s1[3]};
    short8 pa;
#pragma unroll
    for (int t = 0; t < 8; ++t) {
      float s = sq1 + skl[t];
      s = fmaxf(s, 0.2f * s);  // leaky relu (positively homogeneous, log2e pre-folded)
      const float wv = ((mb >> t) & 1u) ? __builtin_amdgcn_exp2f(s) : 0.0f;
      pa[t] = f2bf_native(wv);
    }
#pragma unroll
    for (int c = 0; c < 4; ++c) {
      const short8 bv = *(const short8*)(vts + (cur << 11) + (((c << 4) + lr) << 5) + vread);
      acc[c] = __builtin_amdgcn_mfma_f32_16x16x32_bf16(pa, bv, acc[c], 0, 0, 0);
    }
    accs = __builtin_amdgcn_mfma_f32_16x16x32_bf16(pa, ones, accs, 0, 0, 0);
    __syncthreads();  // drains own-wave vmcnt (staging) + lgkm; all slabs ready
    cur ^= 1;
  }

#pragma unroll
  for (int r = 0; r < 4; ++r) {
    const float s = accs[r];
    const float inv = s > 0.0f ? 1.0f / s : 0.0f;  // fully-masked row -> 0
    const int i = i0w + lc * 4 + r;
#pragma unroll
    for (int c = 0; c < 4; ++c)
      xb[(((size_t)(b * 1024 + i)) << 9) + h * 64 + c * 16 + lr] =
          f2bf(acc[c][r] * inv);
  }
}

extern "C" void kernel_launch(void* const* d_in, const int* in_sizes, int n_in,
                              void* d_out, int out_size, void* d_ws, size_t ws_size,
                              hipStream_t stream) {
  const float* query = (const float*)d_in[0];
  const float* key   = (const float*)d_in[1];
  const float* value = (const float*)d_in[2];
  const int*   mask  = (const int*)d_in[3];
  const float* Wq = (const float*)d_in[4];
  const float* bq = (const float*)d_in[5];
  const float* Wk = (const float*)d_in[6];
  const float* bk = (const float*)d_in[7];
  const float* Wv = (const float*)d_in[8];
  const float* bv = (const float*)d_in[9];
  const float* Wo = (const float*)d_in[10];
  const float* bo = (const float*)d_in[11];
  const float* a  = (const float*)d_in[12];

  // d_out doubles as scratch (fully overwritten by the final GEMM).
  char* oc = (char*)d_out;
  unsigned short* vt = (unsigned short*)(oc + 0);
  unsigned int* mbits = (unsigned int*)(oc + 8388608);
  float* sqv = (float*)(oc + 9437184);
  float* skv = (float*)(oc + 9699328);
  float* Aq  = (float*)(oc + 9961472);
  float* Ak  = (float*)(oc + 9977856);
  float* qbf = (float*)(oc + 9994240);
  float* kbf = (float*)(oc + 9994496);
  // ws: only the attention output (must not alias d_out during final GEMM).
  unsigned short* xb = (unsigned short*)d_ws;  // 8,388,608 bytes

  prep_a_kernel<<<16, 256, 0, stream>>>(Wq, Wk, a, bq, bk, Aq, Ak, qbf, kbf);
  sqsk_kernel<<<256, 256, 0, stream>>>(query, key, Aq, Ak, qbf, kbf, sqv, skv);
  maskbits_kernel<<<32768, 256, 0, stream>>>(mask, mbits);
  gemm_bt<1, 1><<<256, 256, 0, stream>>>((const void*)value, Wv, bv, (void*)vt);
  attn_kernel<<<1024, 256, 0, stream>>>(sqv, skv, (const unsigned char*)mbits, vt, xb);
  gemm_bt<0, 0><<<256, 256, 0, stream>>>((const void*)xb, Wo, bo, d_out);
}

// Round 5
// 135.759 us; speedup vs baseline: 1.1954x; 1.0165x over previous
//
#include <hip/hip_runtime.h>
#include <hip/hip_bf16.h>
#include <stdint.h>

// B=8, N=1024, D=512, H=8, DK=64, ALPHA=0.2
//
// Scratch plan:
//   ws  : xb (attention output, bf16 [8192][512]) @ 0, 8,388,608 bytes.
//   d_out (16,777,216 bytes f32) doubles as scratch; all regions are
//   write-before-read within one call and dead before gemm<0> overwrites:
//     vt   @ 0          8,388,608  (v^T per head: [b][h][dk][n] bf16)
//     mbit @ 8,388,608  1,048,576  (mask bitset, [b][i][128B])
//     sq   @ 9,437,184    262,144  ([b][h][n] f32, pre-scaled by log2e)
//     sk   @ 9,699,328    262,144  (pre-scaled by log2e)
//     AqT  @ 9,961,472     16,384  ([h][512] f32, transposed)
//     AkT  @ 9,977,856     16,384
//     qb   @ 9,994,240        256
//     kb   @ 9,994,496        256

typedef __attribute__((ext_vector_type(8))) short short8;
typedef __attribute__((ext_vector_type(4))) float f32x4;

#define LB __launch_bounds__(256)

__device__ __forceinline__ unsigned short f2bf(float f) {
  unsigned int u = __float_as_uint(f);
  u += 0x7fffu + ((u >> 16) & 1u);
  return (unsigned short)(u >> 16);
}

__device__ __forceinline__ short f2bf_native(float f) {
  union { __hip_bfloat16 h; unsigned short u; } cv;
  cv.h = __float2bfloat16(f);
  return (short)cv.u;
}

// async global->LDS, 16B per lane. lptr = wave-uniform base; gptr = per-lane.
__device__ __forceinline__ void async_cp16(const void* g, void* l) {
  __builtin_amdgcn_global_load_lds(
      (const __attribute__((address_space(1))) unsigned int*)g,
      (__attribute__((address_space(3))) unsigned int*)l, 16, 0, 0);
}

// ---------------- fold attention vector a into Wq/Wk (transposed out) ----------------
// AqT[h][d] = sum_dk Wq[h*64+dk][d] * a[h][dk];  qb[h] = bq[h*64:]·a[h][:64]
__global__ LB void prep_a_kernel(const float* __restrict__ Wq, const float* __restrict__ Wk,
                                 const float* __restrict__ a, const float* __restrict__ bq,
                                 const float* __restrict__ bk,
                                 float* __restrict__ AqT, float* __restrict__ AkT,
                                 float* __restrict__ qb, float* __restrict__ kb) {
  const int t = blockIdx.x * 256 + threadIdx.x;  // 4096 threads: d fast (coalesced), h slow
  const int d = t & 511, h = t >> 9;
  float aq = 0.f, ak = 0.f;
  for (int dk = 0; dk < 64; ++dk) {
    aq += Wq[(size_t)(h * 64 + dk) * 512 + d] * a[h * 128 + dk];
    ak += Wk[(size_t)(h * 64 + dk) * 512 + d] * a[h * 128 + 64 + dk];
  }
  AqT[h * 512 + d] = aq;
  AkT[h * 512 + d] = ak;
  if (d == 0) {
    float s1 = 0.f, s2 = 0.f;
    for (int dk = 0; dk < 64; ++dk) {
      s1 += bq[h * 64 + dk] * a[h * 128 + dk];
      s2 += bk[h * 64 + dk] * a[h * 128 + 64 + dk];
    }
    qb[h] = s1;
    kb[h] = s2;
  }
}

// ---------------- sq/sk: rank-8 projections, d-split 8x, pre-scaled by log2(e) ----------
// Block = 256 threads = (4 rows) x (8 h) x (8 d-chunks of 64); side = blockIdx&1 (q or k).
// Grid 4096. Each thread: 16 unrolled float4-pair loads + 64 FMA; 8-way LDS combine.
__global__ LB void sqsk_kernel(const float* __restrict__ query, const float* __restrict__ key,
                               const float* __restrict__ AqT, const float* __restrict__ AkT,
                               const float* __restrict__ qb, const float* __restrict__ kb,
                               float* __restrict__ sq, float* __restrict__ sk) {
  __shared__ float part[8][33];  // [dc][h*4+row_l], pad -> conflict-free
  const int tid = threadIdx.x;
  const int row_l = tid & 3, h = (tid >> 2) & 7, dc = tid >> 5;
  const int qk = blockIdx.x & 1;
  const int row = (blockIdx.x >> 1) * 4 + row_l;
  const float* X = qk ? key : query;
  const float* W = qk ? AkT : AqT;
  const float* xrow = X + (size_t)row * 512 + dc * 64;
  const float* wrow = W + h * 512 + dc * 64;
  float acc = 0.f;
#pragma unroll
  for (int j = 0; j < 16; ++j) {
    const float4 xv = *(const float4*)(xrow + j * 4);
    const float4 wv = *(const float4*)(wrow + j * 4);
    acc += xv.x * wv.x + xv.y * wv.y + xv.z * wv.z + xv.w * wv.w;
  }
  part[dc][h * 4 + row_l] = acc;
  __syncthreads();
  if (tid < 32) {
    float s = 0.f;
#pragma unroll
    for (int d = 0; d < 8; ++d) s += part[d][tid];
    const int hh = tid >> 2, rl = tid & 3;
    const int rr = (blockIdx.x >> 1) * 4 + rl;
    const int b = rr >> 10, n = rr & 1023;
    const float L2E = 1.44269504088896f;
    float* outp = qk ? sk : sq;
    const float* bias = qk ? kb : qb;
    outp[((size_t)b * 8 + hh) * 1024 + n] = (s + bias[hh]) * L2E;
  }
}

// ---------------- mask (B,N,N) int32 -> bitset ----------------
__global__ LB void maskbits_kernel(const int* __restrict__ mask,
                                   unsigned int* __restrict__ bits) {
  const size_t idx = (size_t)blockIdx.x * 256 + threadIdx.x;
  const unsigned long long bl = __ballot(mask[idx] != 0);
  if ((threadIdx.x & 63) == 0) {
    bits[idx >> 5] = (unsigned int)bl;
    bits[(idx >> 5) + 1] = (unsigned int)(bl >> 32);
  }
}

// ---------------- bf16 MFMA GEMM: C[8192][512] = A @ Bw[512][512]^T + bias
// AF32: A is fp32 (cast to bf16 during staging); else A is bf16.
// MODE 0: C -> fp32 row-major.  MODE 1: C -> bf16 v^T layout [b][h][dk][n].
template <int AF32, int MODE>
__global__ LB void gemm_bt(const void* __restrict__ Ap,
                           const float* __restrict__ Bw,
                           const float* __restrict__ bias, void* __restrict__ outp) {
  __shared__ unsigned short As[128 * 32];
  __shared__ unsigned short Bs[128 * 32];
  const int tid = threadIdx.x;
  const int w = tid >> 6, l = tid & 63;
  const int lr = l & 15, lc = l >> 4;
  const int bm = blockIdx.x >> 2, bn = blockIdx.x & 3;  // grid 256: 64 x 4
  const int m0 = bm * 128, n0 = bn * 128;
  const int wr = (w >> 1) * 64, wc = (w & 1) * 64;
  f32x4 acc[4][4] = {};
  for (int kt = 0; kt < 16; ++kt) {
    const int k0 = kt * 32;
    if (kt) __syncthreads();
#pragma unroll
    for (int it = 0; it < 2; ++it) {
      int idx = it * 256 + tid;  // 0..511
      int row = idx >> 2, gr = idx & 3;
      if (AF32) {
        const float4* src = (const float4*)((const float*)Ap + (size_t)(m0 + row) * 512 + k0 + gr * 8);
        const float4 a0 = src[0], a1 = src[1];
        unsigned short t8[8] = {f2bf(a0.x), f2bf(a0.y), f2bf(a0.z), f2bf(a0.w),
                                f2bf(a1.x), f2bf(a1.y), f2bf(a1.z), f2bf(a1.w)};
        *(short8*)(As + row * 32 + gr * 8) = *(short8*)t8;
      } else {
        *(short8*)(As + row * 32 + gr * 8) =
            *(const short8*)((const unsigned short*)Ap + (size_t)(m0 + row) * 512 + k0 + gr * 8);
      }
      {
        const float4* src = (const float4*)(Bw + (size_t)(n0 + row) * 512 + k0 + gr * 8);
        const float4 b0 = src[0], b1 = src[1];
        unsigned short t8[8] = {f2bf(b0.x), f2bf(b0.y), f2bf(b0.z), f2bf(b0.w),
                                f2bf(b1.x), f2bf(b1.y), f2bf(b1.z), f2bf(b1.w)};
        *(short8*)(Bs + row * 32 + gr * 8) = *(short8*)t8;
      }
    }
    __syncthreads();
    short8 af[4], bfr[4];
#pragma unroll
    for (int g = 0; g < 4; ++g) {
      af[g]  = *(const short8*)(As + (wr + g * 16 + lr) * 32 + lc * 8);
      bfr[g] = *(const short8*)(Bs + (wc + g * 16 + lr) * 32 + lc * 8);
    }
#pragma unroll
    for (int i = 0; i < 4; ++i)
#pragma unroll
      for (int j = 0; j < 4; ++j)
        acc[i][j] = __builtin_amdgcn_mfma_f32_16x16x32_bf16(af[i], bfr[j], acc[i][j], 0, 0, 0);
  }
#pragma unroll
  for (int i = 0; i < 4; ++i) {
#pragma unroll
    for (int j = 0; j < 4; ++j) {
      const int nn = n0 + wc + j * 16 + lr;
      const float bia = bias[nn];
      if (MODE == 0) {
        float* out = (float*)outp;
#pragma unroll
        for (int r = 0; r < 4; ++r) {
          const int mm = m0 + wr + i * 16 + lc * 4 + r;
          out[(size_t)mm * 512 + nn] = acc[i][j][r] + bia;
        }
      } else {
        unsigned short* out = (unsigned short*)outp;
        const int mm0 = m0 + wr + i * 16 + lc * 4;
        const int b = mm0 >> 10, t0 = mm0 & 1023;
        const int h = nn >> 6, dk = nn & 63;
        unsigned long long pk = 0;
#pragma unroll
        for (int r = 0; r < 4; ++r)
          pk |= (unsigned long long)f2bf(acc[i][j][r] + bia) << (16 * r);
        *(unsigned long long*)(out + (((size_t)((b * 8 + h) * 64 + dk)) << 10) + t0) = pk;
      }
    }
  }
}

// ---------------- fused attention, LDS-staged, double-buffered vt ----------------
// Block = 4 waves x 16 i-rows = 64 rows of one (b,h); full j per wave (no combine).
// LDS: vt j-slab dbuf (2x4KB, swizzled), sk (4KB), mask slab (8KB, swizzled).
// sq/sk arrive pre-scaled by log2(e): w = exp2(lrelu(sq_i+sk_j)) * maskbit.
__global__ LB void attn_kernel(const float* __restrict__ sq, const float* __restrict__ sk,
                               const unsigned char* __restrict__ mbits,
                               const unsigned short* __restrict__ vt,
                               unsigned short* __restrict__ xb) {
  __shared__ char smem[20480];
  unsigned short* vts = (unsigned short*)smem;  // [2][64dk][32j] bf16, chunk-swizzled
  float* sks = (float*)(smem + 8192);           // [1024] f32
  char* mks = smem + 12288;                     // [64 rows][128B], byte-swizzled
  const int tid = threadIdx.x;
  const int w = tid >> 6, l = tid & 63;
  const int lr = l & 15, lc = l >> 4;
  const int bid = blockIdx.x;  // 1024 blocks: bh(64) x iblk(16); iblk fast for L2 share
  const int bh = bid >> 4, iblk = bid & 15;
  const int b = bh >> 3, h = bh & 7;
  const int i0b = iblk * 64, i0w = i0b + (w << 4);
  const float* sqp = sq + (size_t)bh * 1024;
  const float* skp = sk + (size_t)bh * 1024;
  const unsigned short* vtp = vt + ((size_t)bh << 16);
  const unsigned char* mrow = mbits + ((size_t)b << 17);

  // ---- prologue staging (async, drained by the syncthreads below)
  // sk: wave w covers f32 idx [w*256, w*256+256)
  async_cp16(skp + (w << 8) + l * 4, sks + (w << 8));
  // mask slab: 64 rows x 128B, swizzled store: LDS[row][q] = M[row][q ^ ((row&7)<<4)]
  {
    const int row0 = (w << 4) + (l >> 3);
    const int c0 = (l & 7) ^ (row0 & 7);
    async_cp16(mrow + (size_t)(i0b + row0) * 128 + (c0 << 4), mks + (w << 11));
    const int row1 = row0 + 8;
    const int c1 = (l & 7) ^ (row1 & 7);
    async_cp16(mrow + (size_t)(i0b + row1) * 128 + (c1 << 4), mks + (w << 11) + 1024);
  }
  // vt slab stage: [64 dk][32 j], source-swizzled: chunk' = chunk ^ ((dk>>1)&3)
  const int st_dk = (w << 4) + (l >> 2);
  const int st_ch = (l & 3) ^ ((st_dk >> 1) & 3);
  const unsigned short* st_base = vtp + st_dk * 1024 + st_ch * 8;
  async_cp16(st_base, vts + (w << 9));  // jb = 0 into buf 0

  const float sq1 = sqp[i0w + lr];
  __syncthreads();

  f32x4 acc[4] = {};
  f32x4 accs = {};
  short8 ones;
#pragma unroll
  for (int t = 0; t < 8; ++t) ones[t] = (short)0x3f80;  // bf16 1.0
  const int rowl = (w << 4) + lr;
  const int mrowbase = rowl << 7;
  const int rxor = (rowl & 7) << 4;
  const int vread = ((lc ^ ((lr >> 1) & 3)) << 3);

  int cur = 0;
  for (int jt = 0; jt < 32; ++jt) {
    const int jb = jt * 32;
    if (jt < 31)  // stage next slab into the other buffer
      async_cp16(st_base + jb + 32, vts + ((cur ^ 1) << 11) + (w << 9));
    // scores for this wave's 16 rows x 32 j
    const unsigned int mb = (unsigned char)mks[mrowbase + ((jt * 4 + lc) ^ rxor)];
    const f32x4 s0 = *(const f32x4*)(sks + jb + lc * 8);
    const f32x4 s1 = *(const f32x4*)(sks + jb + lc * 8 + 4);
    const float skl[8] = {s0[0], s0[1], s0[2], s0[3], s1[0], s1[1], s1[2], s1[3]};
    short8 pa;
#pragma unroll
    for (int t = 0; t < 8; ++t) {
      float s = sq1 + skl[t];
      s = fmaxf(s, 0.2f * s);  // leaky relu (positively homogeneous, log2e pre-folded)
      const float wv = ((mb >> t) & 1u) ? __builtin_amdgcn_exp2f(s) : 0.0f;
      pa[t] = f2bf_native(wv);
    }
#pragma unroll
    for (int c = 0; c < 4; ++c) {
      const short8 bv = *(const short8*)(vts + (cur << 11) + (((c << 4) + lr) << 5) + vread);
      acc[c] = __builtin_amdgcn_mfma_f32_16x16x32_bf16(pa, bv, acc[c], 0, 0, 0);
    }
    accs = __builtin_amdgcn_mfma_f32_16x16x32_bf16(pa, ones, accs, 0, 0, 0);
    __syncthreads();  // drains own-wave vmcnt (staging) + lgkm; all slabs ready
    cur ^= 1;
  }

#pragma unroll
  for (int r = 0; r < 4; ++r) {
    const float s = accs[r];
    const float inv = s > 0.0f ? 1.0f / s : 0.0f;  // fully-masked row -> 0
    const int i = i0w + lc * 4 + r;
#pragma unroll
    for (int c = 0; c < 4; ++c)
      xb[(((size_t)(b * 1024 + i)) << 9) + h * 64 + c * 16 + lr] =
          f2bf(acc[c][r] * inv);
  }
}

extern "C" void kernel_launch(void* const* d_in, const int* in_sizes, int n_in,
                              void* d_out, int out_size, void* d_ws, size_t ws_size,
                              hipStream_t stream) {
  const float* query = (const float*)d_in[0];
  const float* key   = (const float*)d_in[1];
  const float* value = (const float*)d_in[2];
  const int*   mask  = (const int*)d_in[3];
  const float* Wq = (const float*)d_in[4];
  const float* bq = (const float*)d_in[5];
  const float* Wk = (const float*)d_in[6];
  const float* bk = (const float*)d_in[7];
  const float* Wv = (const float*)d_in[8];
  const float* bv = (const float*)d_in[9];
  const float* Wo = (const float*)d_in[10];
  const float* bo = (const float*)d_in[11];
  const float* a  = (const float*)d_in[12];

  // d_out doubles as scratch (fully overwritten by the final GEMM).
  char* oc = (char*)d_out;
  unsigned short* vt = (unsigned short*)(oc + 0);
  unsigned int* mbits = (unsigned int*)(oc + 8388608);
  float* sqv = (float*)(oc + 9437184);
  float* skv = (float*)(oc + 9699328);
  float* AqT = (float*)(oc + 9961472);
  float* AkT = (float*)(oc + 9977856);
  float* qbf = (float*)(oc + 9994240);
  float* kbf = (float*)(oc + 9994496);
  // ws: only the attention output (must not alias d_out during final GEMM).
  unsigned short* xb = (unsigned short*)d_ws;  // 8,388,608 bytes

  prep_a_kernel<<<16, 256, 0, stream>>>(Wq, Wk, a, bq, bk, AqT, AkT, qbf, kbf);
  sqsk_kernel<<<4096, 256, 0, stream>>>(query, key, AqT, AkT, qbf, kbf, sqv, skv);
  maskbits_kernel<<<32768, 256, 0, stream>>>(mask, mbits);
  gemm_bt<1, 1><<<256, 256, 0, stream>>>((const void*)value, Wv, bv, (void*)vt);
  attn_kernel<<<1024, 256, 0, stream>>>(sqv, skv, (const unsigned char*)mbits, vt, xb);
  gemm_bt<0, 0><<<256, 256, 0, stream>>>((const void*)xb, Wo, bo, d_out);
}

// Round 6
// 108.492 us; speedup vs baseline: 1.4958x; 1.2513x over previous
//
#include <hip/hip_runtime.h>
#include <hip/hip_bf16.h>
#include <stdint.h>

// B=8, N=1024, D=512, H=8, DK=64, ALPHA=0.2
//
// Scratch plan:
//   ws  : xb (attention output, bf16 [8192][512]) @ 0, 8,388,608 bytes.
//   d_out (16,777,216 bytes f32) doubles as scratch; all regions are
//   write-before-read within one call and dead before gemm<0> overwrites:
//     vt    @ 0          8,388,608  (v^T per head: [b][h][dk][n] bf16)
//     mbit  @ 8,388,608  1,048,576  (mask bitset, [b][i][128B])
//     sq    @ 9,437,184    262,144  ([b][h][n] f32, pre-scaled by log2e)
//     sk    @ 9,699,328    262,144  (pre-scaled by log2e)
//     Bfrag @ 9,961,472     16,384  (bf16 [16 kstep][64 lane][8] MFMA B-frags,
//                                    cols 0-7 = Aq*L2E, cols 8-15 = Ak*L2E)
//     qkb   @ 9,977,856         64  (f32[16]: qb*L2E, kb*L2E)

typedef __attribute__((ext_vector_type(8))) short short8;
typedef __attribute__((ext_vector_type(4))) float f32x4;

#define LB __launch_bounds__(256)

__device__ __forceinline__ unsigned short f2bf(float f) {
  unsigned int u = __float_as_uint(f);
  u += 0x7fffu + ((u >> 16) & 1u);
  return (unsigned short)(u >> 16);
}

__device__ __forceinline__ short f2bf_native(float f) {
  union { __hip_bfloat16 h; unsigned short u; } cv;
  cv.h = __float2bfloat16(f);
  return (short)cv.u;
}

// async global->LDS, 16B per lane. lptr = wave-uniform base; gptr = per-lane.
__device__ __forceinline__ void async_cp16(const void* g, void* l) {
  __builtin_amdgcn_global_load_lds(
      (const __attribute__((address_space(1))) unsigned int*)g,
      (__attribute__((address_space(3))) unsigned int*)l, 16, 0, 0);
}

// ---------------- fold attention vector a into Wq/Wk -> MFMA B-fragment buffer --------
// B[k][n] = (n<8 ? Aq[n][k] : Ak[n-8][k]) * L2E, stored in 16x16x32 B-frag lane order:
// Bfrag[(kstep*64 + lane)*8 + t] with k = kstep*32 + (lane>>4)*8 + t, n = lane&15.
__global__ LB void prep_a_kernel(const float* __restrict__ Wq, const float* __restrict__ Wk,
                                 const float* __restrict__ a, const float* __restrict__ bq,
                                 const float* __restrict__ bk,
                                 unsigned short* __restrict__ Bfrag,
                                 float* __restrict__ qkb) {
  const int t = blockIdx.x * 256 + threadIdx.x;  // 4096 threads: d fast (coalesced), h slow
  const int d = t & 511, h = t >> 9;
  float aq = 0.f, ak = 0.f;
#pragma unroll 4
  for (int dk = 0; dk < 64; ++dk) {
    aq += Wq[(size_t)(h * 64 + dk) * 512 + d] * a[h * 128 + dk];
    ak += Wk[(size_t)(h * 64 + dk) * 512 + d] * a[h * 128 + 64 + dk];
  }
  const float L2E = 1.4426950408889634f;
  const int ks = d >> 5, lch = (d >> 3) & 3, tt = d & 7;
  Bfrag[((ks * 64 + (lch << 4) + h) << 3) + tt] = f2bf(aq * L2E);
  Bfrag[((ks * 64 + (lch << 4) + 8 + h) << 3) + tt] = f2bf(ak * L2E);
  if (d == 0) {
    float s1 = 0.f, s2 = 0.f;
    for (int dk = 0; dk < 64; ++dk) {
      s1 += bq[h * 64 + dk] * a[h * 128 + dk];
      s2 += bk[h * 64 + dk] * a[h * 128 + 64 + dk];
    }
    qkb[h] = s1 * L2E;
    qkb[8 + h] = s2 * L2E;
  }
}

// ---------------- sq/sk via MFMA skinny GEMM ----------------
// Block = 4 waves = one 16-row tile x 4 K-quarters (128 each); grid 512.
// Wave: preload 4 B-frags, loop 4 ksteps {load q/k A-frags coalesced, cvt, 2 MFMA}.
// K-quarter partials combined through pad-9 LDS; wave 0 writes sq/sk (+bias).
__global__ LB void sqsk_kernel(const float* __restrict__ query, const float* __restrict__ key,
                               const unsigned short* __restrict__ Bfrag,
                               const float* __restrict__ qkb,
                               float* __restrict__ sq, float* __restrict__ sk) {
  __shared__ float comb[3 * 64 * 9];  // 6912 B, stride-9 -> 2-way (free)
  const int tid = threadIdx.x, wv = tid >> 6, l = tid & 63;
  const int m0 = blockIdx.x * 16;
  const int k0 = wv * 128;
  short8 bf[4];
#pragma unroll
  for (int ks = 0; ks < 4; ++ks)
    bf[ks] = *(const short8*)(Bfrag + (((wv * 4 + ks) * 64 + l) << 3));
  const float* qbase = query + (size_t)(m0 + (l & 15)) * 512 + k0 + ((l >> 4) << 3);
  const float* kbase = key + (size_t)(m0 + (l & 15)) * 512 + k0 + ((l >> 4) << 3);
  f32x4 cq = {}, ck = {};
#pragma unroll
  for (int ks = 0; ks < 4; ++ks) {
    const float4 q0 = *(const float4*)(qbase + ks * 32);
    const float4 q1 = *(const float4*)(qbase + ks * 32 + 4);
    const float4 k0v = *(const float4*)(kbase + ks * 32);
    const float4 k1v = *(const float4*)(kbase + ks * 32 + 4);
    short8 aq, ak;
    aq[0] = f2bf_native(q0.x); aq[1] = f2bf_native(q0.y);
    aq[2] = f2bf_native(q0.z); aq[3] = f2bf_native(q0.w);
    aq[4] = f2bf_native(q1.x); aq[5] = f2bf_native(q1.y);
    aq[6] = f2bf_native(q1.z); aq[7] = f2bf_native(q1.w);
    ak[0] = f2bf_native(k0v.x); ak[1] = f2bf_native(k0v.y);
    ak[2] = f2bf_native(k0v.z); ak[3] = f2bf_native(k0v.w);
    ak[4] = f2bf_native(k1v.x); ak[5] = f2bf_native(k1v.y);
    ak[6] = f2bf_native(k1v.z); ak[7] = f2bf_native(k1v.w);
    cq = __builtin_amdgcn_mfma_f32_16x16x32_bf16(aq, bf[ks], cq, 0, 0, 0);
    ck = __builtin_amdgcn_mfma_f32_16x16x32_bf16(ak, bf[ks], ck, 0, 0, 0);
  }
  if (wv) {
    float* p = comb + ((wv - 1) * 64 + l) * 9;
#pragma unroll
    for (int r = 0; r < 4; ++r) { p[r] = cq[r]; p[4 + r] = ck[r]; }
  }
  __syncthreads();
  if (wv == 0) {
#pragma unroll
    for (int j = 0; j < 3; ++j) {
      const float* p = comb + (j * 64 + l) * 9;
#pragma unroll
      for (int r = 0; r < 4; ++r) { cq[r] += p[r]; ck[r] += p[4 + r]; }
    }
    const int col = l & 15;
    const int mbase = m0 + ((l >> 4) << 2);
    const int b = mbase >> 10;  // 16-row tile never straddles a batch boundary
    const float bia = qkb[col];
    if (col < 8) {
      float* out = sq + ((size_t)b * 8 + col) * 1024;
#pragma unroll
      for (int r = 0; r < 4; ++r) out[(mbase + r) & 1023] = cq[r] + bia;
    } else {
      float* out = sk + ((size_t)b * 8 + (col - 8)) * 1024;
#pragma unroll
      for (int r = 0; r < 4; ++r) out[(mbase + r) & 1023] = ck[r] + bia;
    }
  }
}

// ---------------- mask (B,N,N) int32 -> bitset ----------------
__global__ LB void maskbits_kernel(const int* __restrict__ mask,
                                   unsigned int* __restrict__ bits) {
  const size_t idx = (size_t)blockIdx.x * 256 + threadIdx.x;
  const unsigned long long bl = __ballot(mask[idx] != 0);
  if ((threadIdx.x & 63) == 0) {
    bits[idx >> 5] = (unsigned int)bl;
    bits[(idx >> 5) + 1] = (unsigned int)(bl >> 32);
  }
}

// ---------------- bf16 MFMA GEMM: C[8192][512] = A @ Bw[512][512]^T + bias
// AF32: A is fp32 (cast to bf16 during staging); else A is bf16.
// MODE 0: C -> fp32 row-major.  MODE 1: C -> bf16 v^T layout [b][h][dk][n].
template <int AF32, int MODE>
__global__ LB void gemm_bt(const void* __restrict__ Ap,
                           const float* __restrict__ Bw,
                           const float* __restrict__ bias, void* __restrict__ outp) {
  __shared__ unsigned short As[128 * 32];
  __shared__ unsigned short Bs[128 * 32];
  const int tid = threadIdx.x;
  const int w = tid >> 6, l = tid & 63;
  const int lr = l & 15, lc = l >> 4;
  const int bm = blockIdx.x >> 2, bn = blockIdx.x & 3;  // grid 256: 64 x 4
  const int m0 = bm * 128, n0 = bn * 128;
  const int wr = (w >> 1) * 64, wc = (w & 1) * 64;
  f32x4 acc[4][4] = {};
  for (int kt = 0; kt < 16; ++kt) {
    const int k0 = kt * 32;
    if (kt) __syncthreads();
#pragma unroll
    for (int it = 0; it < 2; ++it) {
      int idx = it * 256 + tid;  // 0..511
      int row = idx >> 2, gr = idx & 3;
      if (AF32) {
        const float4* src = (const float4*)((const float*)Ap + (size_t)(m0 + row) * 512 + k0 + gr * 8);
        const float4 a0 = src[0], a1 = src[1];
        unsigned short t8[8] = {f2bf(a0.x), f2bf(a0.y), f2bf(a0.z), f2bf(a0.w),
                                f2bf(a1.x), f2bf(a1.y), f2bf(a1.z), f2bf(a1.w)};
        *(short8*)(As + row * 32 + gr * 8) = *(short8*)t8;
      } else {
        *(short8*)(As + row * 32 + gr * 8) =
            *(const short8*)((const unsigned short*)Ap + (size_t)(m0 + row) * 512 + k0 + gr * 8);
      }
      {
        const float4* src = (const float4*)(Bw + (size_t)(n0 + row) * 512 + k0 + gr * 8);
        const float4 b0 = src[0], b1 = src[1];
        unsigned short t8[8] = {f2bf(b0.x), f2bf(b0.y), f2bf(b0.z), f2bf(b0.w),
                                f2bf(b1.x), f2bf(b1.y), f2bf(b1.z), f2bf(b1.w)};
        *(short8*)(Bs + row * 32 + gr * 8) = *(short8*)t8;
      }
    }
    __syncthreads();
    short8 af[4], bfr[4];
#pragma unroll
    for (int g = 0; g < 4; ++g) {
      af[g]  = *(const short8*)(As + (wr + g * 16 + lr) * 32 + lc * 8);
      bfr[g] = *(const short8*)(Bs + (wc + g * 16 + lr) * 32 + lc * 8);
    }
#pragma unroll
    for (int i = 0; i < 4; ++i)
#pragma unroll
      for (int j = 0; j < 4; ++j)
        acc[i][j] = __builtin_amdgcn_mfma_f32_16x16x32_bf16(af[i], bfr[j], acc[i][j], 0, 0, 0);
  }
#pragma unroll
  for (int i = 0; i < 4; ++i) {
#pragma unroll
    for (int j = 0; j < 4; ++j) {
      const int nn = n0 + wc + j * 16 + lr;
      const float bia = bias[nn];
      if (MODE == 0) {
        float* out = (float*)outp;
#pragma unroll
        for (int r = 0; r < 4; ++r) {
          const int mm = m0 + wr + i * 16 + lc * 4 + r;
          out[(size_t)mm * 512 + nn] = acc[i][j][r] + bia;
        }
      } else {
        unsigned short* out = (unsigned short*)outp;
        const int mm0 = m0 + wr + i * 16 + lc * 4;
        const int b = mm0 >> 10, t0 = mm0 & 1023;
        const int h = nn >> 6, dk = nn & 63;
        unsigned long long pk = 0;
#pragma unroll
        for (int r = 0; r < 4; ++r)
          pk |= (unsigned long long)f2bf(acc[i][j][r] + bia) << (16 * r);
        *(unsigned long long*)(out + (((size_t)((b * 8 + h) * 64 + dk)) << 10) + t0) = pk;
      }
    }
  }
}

// ---------------- fused attention, LDS-staged, double-buffered vt ----------------
// Block = 4 waves x 16 i-rows = 64 rows of one (b,h); full j per wave (no combine).
// LDS: vt j-slab dbuf (2x4KB, swizzled), sk (4KB), mask slab (8KB, swizzled).
// sq/sk arrive pre-scaled by log2(e): w = exp2(lrelu(sq_i+sk_j)) * maskbit.
__global__ LB void attn_kernel(const float* __restrict__ sq, const float* __restrict__ sk,
                               const unsigned char* __restrict__ mbits,
                               const unsigned short* __restrict__ vt,
                               unsigned short* __restrict__ xb) {
  __shared__ char smem[20480];
  unsigned short* vts = (unsigned short*)smem;  // [2][64dk][32j] bf16, chunk-swizzled
  float* sks = (float*)(smem + 8192);           // [1024] f32
  char* mks = smem + 12288;                     // [64 rows][128B], byte-swizzled
  const int tid = threadIdx.x;
  const int w = tid >> 6, l = tid & 63;
  const int lr = l & 15, lc = l >> 4;
  const int bid = blockIdx.x;  // 1024 blocks: bh(64) x iblk(16); iblk fast for L2 share
  const int bh = bid >> 4, iblk = bid & 15;
  const int b = bh >> 3, h = bh & 7;
  const int i0b = iblk * 64, i0w = i0b + (w << 4);
  const float* sqp = sq + (size_t)bh * 1024;
  const float* skp = sk + (size_t)bh * 1024;
  const unsigned short* vtp = vt + ((size_t)bh << 16);
  const unsigned char* mrow = mbits + ((size_t)b << 17);

  // ---- prologue staging (async, drained by the syncthreads below)
  // sk: wave w covers f32 idx [w*256, w*256+256)
  async_cp16(skp + (w << 8) + l * 4, sks + (w << 8));
  // mask slab: 64 rows x 128B, swizzled store: LDS[row][q] = M[row][q ^ ((row&7)<<4)]
  {
    const int row0 = (w << 4) + (l >> 3);
    const int c0 = (l & 7) ^ (row0 & 7);
    async_cp16(mrow + (size_t)(i0b + row0) * 128 + (c0 << 4), mks + (w << 11));
    const int row1 = row0 + 8;
    const int c1 = (l & 7) ^ (row1 & 7);
    async_cp16(mrow + (size_t)(i0b + row1) * 128 + (c1 << 4), mks + (w << 11) + 1024);
  }
  // vt slab stage: [64 dk][32 j], source-swizzled: chunk' = chunk ^ ((dk>>1)&3)
  const int st_dk = (w << 4) + (l >> 2);
  const int st_ch = (l & 3) ^ ((st_dk >> 1) & 3);
  const unsigned short* st_base = vtp + st_dk * 1024 + st_ch * 8;
  async_cp16(st_base, vts + (w << 9));  // jb = 0 into buf 0

  const float sq1 = sqp[i0w + lr];
  __syncthreads();

  f32x4 acc[4] = {};
  f32x4 accs = {};
  short8 ones;
#pragma unroll
  for (int t = 0; t < 8; ++t) ones[t] = (short)0x3f80;  // bf16 1.0
  const int rowl = (w << 4) + lr;
  const int mrowbase = rowl << 7;
  const int rxor = (rowl & 7) << 4;
  const int vread = ((lc ^ ((lr >> 1) & 3)) << 3);

  int cur = 0;
  for (int jt = 0; jt < 32; ++jt) {
    const int jb = jt * 32;
    if (jt < 31)  // stage next slab into the other buffer
      async_cp16(st_base + jb + 32, vts + ((cur ^ 1) << 11) + (w << 9));
    // scores for this wave's 16 rows x 32 j
    const unsigned int mb = (unsigned char)mks[mrowbase + ((jt * 4 + lc) ^ rxor)];
    const f32x4 s0 = *(const f32x4*)(sks + jb + lc * 8);
    const f32x4 s1 = *(const f32x4*)(sks + jb + lc * 8 + 4);
    const float skl[8] = {s0[0], s0[1], s0[2], s0[3], s1[0], s1[1], s1[2], s1[3]};
    short8 pa;
#pragma unroll
    for (int t = 0; t < 8; ++t) {
      float s = sq1 + skl[t];
      s = fmaxf(s, 0.2f * s);  // leaky relu (positively homogeneous, log2e pre-folded)
      const float wv = ((mb >> t) & 1u) ? __builtin_amdgcn_exp2f(s) : 0.0f;
      pa[t] = f2bf_native(wv);
    }
#pragma unroll
    for (int c = 0; c < 4; ++c) {
      const short8 bv = *(const short8*)(vts + (cur << 11) + (((c << 4) + lr) << 5) + vread);
      acc[c] = __builtin_amdgcn_mfma_f32_16x16x32_bf16(pa, bv, acc[c], 0, 0, 0);
    }
    accs = __builtin_amdgcn_mfma_f32_16x16x32_bf16(pa, ones, accs, 0, 0, 0);
    __syncthreads();  // drains own-wave vmcnt (staging) + lgkm; all slabs ready
    cur ^= 1;
  }

#pragma unroll
  for (int r = 0; r < 4; ++r) {
    const float s = accs[r];
    const float inv = s > 0.0f ? 1.0f / s : 0.0f;  // fully-masked row -> 0
    const int i = i0w + lc * 4 + r;
#pragma unroll
    for (int c = 0; c < 4; ++c)
      xb[(((size_t)(b * 1024 + i)) << 9) + h * 64 + c * 16 + lr] =
          f2bf(acc[c][r] * inv);
  }
}

extern "C" void kernel_launch(void* const* d_in, const int* in_sizes, int n_in,
                              void* d_out, int out_size, void* d_ws, size_t ws_size,
                              hipStream_t stream) {
  const float* query = (const float*)d_in[0];
  const float* key   = (const float*)d_in[1];
  const float* value = (const float*)d_in[2];
  const int*   mask  = (const int*)d_in[3];
  const float* Wq = (const float*)d_in[4];
  const float* bq = (const float*)d_in[5];
  const float* Wk = (const float*)d_in[6];
  const float* bk = (const float*)d_in[7];
  const float* Wv = (const float*)d_in[8];
  const float* bv = (const float*)d_in[9];
  const float* Wo = (const float*)d_in[10];
  const float* bo = (const float*)d_in[11];
  const float* a  = (const float*)d_in[12];

  // d_out doubles as scratch (fully overwritten by the final GEMM).
  char* oc = (char*)d_out;
  unsigned short* vt = (unsigned short*)(oc + 0);
  unsigned int* mbits = (unsigned int*)(oc + 8388608);
  float* sqv = (float*)(oc + 9437184);
  float* skv = (float*)(oc + 9699328);
  unsigned short* Bfrag = (unsigned short*)(oc + 9961472);
  float* qkb = (float*)(oc + 9977856);
  // ws: only the attention output (must not alias d_out during final GEMM).
  unsigned short* xb = (unsigned short*)d_ws;  // 8,388,608 bytes

  prep_a_kernel<<<16, 256, 0, stream>>>(Wq, Wk, a, bq, bk, Bfrag, qkb);
  sqsk_kernel<<<512, 256, 0, stream>>>(query, key, Bfrag, qkb, sqv, skv);
  maskbits_kernel<<<32768, 256, 0, stream>>>(mask, mbits);
  gemm_bt<1, 1><<<256, 256, 0, stream>>>((const void*)value, Wv, bv, (void*)vt);
  attn_kernel<<<1024, 256, 0, stream>>>(sqv, skv, (const unsigned char*)mbits, vt, xb);
  gemm_bt<0, 0><<<256, 256, 0, stream>>>((const void*)xb, Wo, bo, d_out);
}

// Round 7
// 106.023 us; speedup vs baseline: 1.5306x; 1.0233x over previous
//
#include <hip/hip_runtime.h>
#include <hip/hip_bf16.h>
#include <stdint.h>

// B=8, N=1024, D=512, H=8, DK=64, ALPHA=0.2
//
// Scratch plan:
//   ws  : xb (attention output, bf16 [8192][512]) @ 0, 8,388,608 bytes.
//   d_out (16,777,216 bytes f32) doubles as scratch; all regions are
//   write-before-read within one call and dead before gemm<0> overwrites:
//     vt    @ 0          8,388,608  (v^T per head: [b][h][dk][n] bf16)
//     mbit  @ 8,388,608  1,048,576  (mask bitset, [b][i][128B])
//     sq    @ 9,437,184    262,144  ([b][h][n] f32, pre-scaled by log2e)
//     sk    @ 9,699,328    262,144  (pre-scaled by log2e)
//     Bfrag @ 9,961,472     16,384  (bf16 MFMA B-frags for sqsk)
//     qkb   @ 9,977,856         64  (f32[16]: qb*L2E, kb*L2E)

typedef __attribute__((ext_vector_type(8))) short short8;
typedef __attribute__((ext_vector_type(4))) float f32x4;

#define LB __launch_bounds__(256)

union U8 { unsigned u[4]; short8 s; uint4 v; };
union U2 { unsigned u[2]; uint2 v; };

__device__ __forceinline__ unsigned short f2bf(float f) {
  unsigned int u = __float_as_uint(f);
  u += 0x7fffu + ((u >> 16) & 1u);
  return (unsigned short)(u >> 16);
}

// v_cvt_pk_bf16_f32: lo16 = bf16(a), hi16 = bf16(b), RNE (bit-identical to f2bf)
__device__ __forceinline__ unsigned cvt_pk(float a, float b) {
  unsigned r;
  asm("v_cvt_pk_bf16_f32 %0, %1, %2" : "=v"(r) : "v"(a), "v"(b));
  return r;
}

// async global->LDS, 16B per lane. lptr = wave-uniform base; gptr = per-lane.
__device__ __forceinline__ void async_cp16(const void* g, void* l) {
  __builtin_amdgcn_global_load_lds(
      (const __attribute__((address_space(1))) unsigned int*)g,
      (__attribute__((address_space(3))) unsigned int*)l, 16, 0, 0);
}

// ---------------- fold attention vector a into Wq/Wk -> MFMA B-fragment buffer --------
__global__ LB void prep_a_kernel(const float* __restrict__ Wq, const float* __restrict__ Wk,
                                 const float* __restrict__ a, const float* __restrict__ bq,
                                 const float* __restrict__ bk,
                                 unsigned short* __restrict__ Bfrag,
                                 float* __restrict__ qkb) {
  const int t = blockIdx.x * 256 + threadIdx.x;  // 4096 threads: d fast, h slow
  const int d = t & 511, h = t >> 9;
  float aq = 0.f, ak = 0.f;
#pragma unroll 4
  for (int dk = 0; dk < 64; ++dk) {
    aq += Wq[(size_t)(h * 64 + dk) * 512 + d] * a[h * 128 + dk];
    ak += Wk[(size_t)(h * 64 + dk) * 512 + d] * a[h * 128 + 64 + dk];
  }
  const float L2E = 1.4426950408889634f;
  const int ks = d >> 5, lch = (d >> 3) & 3, tt = d & 7;
  Bfrag[((ks * 64 + (lch << 4) + h) << 3) + tt] = f2bf(aq * L2E);
  Bfrag[((ks * 64 + (lch << 4) + 8 + h) << 3) + tt] = f2bf(ak * L2E);
  if (d == 0) {
    float s1 = 0.f, s2 = 0.f;
    for (int dk = 0; dk < 64; ++dk) {
      s1 += bq[h * 64 + dk] * a[h * 128 + dk];
      s2 += bk[h * 64 + dk] * a[h * 128 + 64 + dk];
    }
    qkb[h] = s1 * L2E;
    qkb[8 + h] = s2 * L2E;
  }
}

// ---------------- sq/sk via MFMA skinny GEMM ----------------
__global__ LB void sqsk_kernel(const float* __restrict__ query, const float* __restrict__ key,
                               const unsigned short* __restrict__ Bfrag,
                               const float* __restrict__ qkb,
                               float* __restrict__ sq, float* __restrict__ sk) {
  __shared__ float comb[3 * 64 * 9];
  const int tid = threadIdx.x, wv = tid >> 6, l = tid & 63;
  const int m0 = blockIdx.x * 16;
  const int k0 = wv * 128;
  short8 bf[4];
#pragma unroll
  for (int ks = 0; ks < 4; ++ks)
    bf[ks] = *(const short8*)(Bfrag + (((wv * 4 + ks) * 64 + l) << 3));
  const float* qbase = query + (size_t)(m0 + (l & 15)) * 512 + k0 + ((l >> 4) << 3);
  const float* kbase = key + (size_t)(m0 + (l & 15)) * 512 + k0 + ((l >> 4) << 3);
  f32x4 cq = {}, ck = {};
#pragma unroll
  for (int ks = 0; ks < 4; ++ks) {
    const float4 q0 = *(const float4*)(qbase + ks * 32);
    const float4 q1 = *(const float4*)(qbase + ks * 32 + 4);
    const float4 k0v = *(const float4*)(kbase + ks * 32);
    const float4 k1v = *(const float4*)(kbase + ks * 32 + 4);
    U8 aq, ak;
    aq.u[0] = cvt_pk(q0.x, q0.y); aq.u[1] = cvt_pk(q0.z, q0.w);
    aq.u[2] = cvt_pk(q1.x, q1.y); aq.u[3] = cvt_pk(q1.z, q1.w);
    ak.u[0] = cvt_pk(k0v.x, k0v.y); ak.u[1] = cvt_pk(k0v.z, k0v.w);
    ak.u[2] = cvt_pk(k1v.x, k1v.y); ak.u[3] = cvt_pk(k1v.z, k1v.w);
    cq = __builtin_amdgcn_mfma_f32_16x16x32_bf16(aq.s, bf[ks], cq, 0, 0, 0);
    ck = __builtin_amdgcn_mfma_f32_16x16x32_bf16(ak.s, bf[ks], ck, 0, 0, 0);
  }
  if (wv) {
    float* p = comb + ((wv - 1) * 64 + l) * 9;
#pragma unroll
    for (int r = 0; r < 4; ++r) { p[r] = cq[r]; p[4 + r] = ck[r]; }
  }
  __syncthreads();
  if (wv == 0) {
#pragma unroll
    for (int j = 0; j < 3; ++j) {
      const float* p = comb + (j * 64 + l) * 9;
#pragma unroll
      for (int r = 0; r < 4; ++r) { cq[r] += p[r]; ck[r] += p[4 + r]; }
    }
    const int col = l & 15;
    const int mbase = m0 + ((l >> 4) << 2);
    const int b = mbase >> 10;
    const float bia = qkb[col];
    if (col < 8) {
      float* out = sq + ((size_t)b * 8 + col) * 1024;
#pragma unroll
      for (int r = 0; r < 4; ++r) out[(mbase + r) & 1023] = cq[r] + bia;
    } else {
      float* out = sk + ((size_t)b * 8 + (col - 8)) * 1024;
#pragma unroll
      for (int r = 0; r < 4; ++r) out[(mbase + r) & 1023] = ck[r] + bia;
    }
  }
}

// ---------------- mask (B,N,N) int32 -> bitset ----------------
__global__ LB void maskbits_kernel(const int* __restrict__ mask,
                                   unsigned int* __restrict__ bits) {
  const size_t idx = (size_t)blockIdx.x * 256 + threadIdx.x;
  const unsigned long long bl = __ballot(mask[idx] != 0);
  if ((threadIdx.x & 63) == 0) {
    bits[idx >> 5] = (unsigned int)bl;
    bits[(idx >> 5) + 1] = (unsigned int)(bl >> 32);
  }
}

// ---------------- bf16 MFMA GEMM: C[8192][512] = A @ Bw[512][512]^T + bias
// 32x128 tiles, grid 1024 (4 blocks/CU). XOR-swizzled LDS (ch ^ (row>>1)&3).
// AF32: A is fp32 (cvt_pk during staging); else A is bf16.
// MODE 0: C -> fp32 row-major.  MODE 1: C -> bf16 v^T layout [b][h][dk][n].
template <int AF32, int MODE>
__global__ LB void gemm_bt(const void* __restrict__ Ap,
                           const float* __restrict__ Bw,
                           const float* __restrict__ bias, void* __restrict__ outp) {
  __shared__ unsigned short As[32 * 32];
  __shared__ unsigned short Bs[128 * 32];
  const int tid = threadIdx.x;
  const int w = tid >> 6, l = tid & 63;
  const int lr = l & 15, lc = l >> 4;
  const int bm = blockIdx.x >> 2, bn = blockIdx.x & 3;  // 256 x 4
  const int m0 = bm * 32, n0 = bn * 128;
  const int wr = (w & 1) * 16, wc = (w >> 1) * 64;
  const int rch = (lc ^ ((lr >> 1) & 3)) << 3;  // swizzled read chunk
  f32x4 acc[4] = {};
  for (int kt = 0; kt < 16; ++kt) {
    const int k0 = kt * 32;
    if (kt) __syncthreads();
    // ---- stage A (32 rows x 32 k): 128 tasks
    if (tid < 128) {
      const int row = tid >> 2, gr = tid & 3;
      const int sch = (gr ^ ((row >> 1) & 3)) << 3;
      if (AF32) {
        const float4* src = (const float4*)((const float*)Ap + (size_t)(m0 + row) * 512 + k0 + gr * 8);
        const float4 a0 = src[0], a1 = src[1];
        U8 t8;
        t8.u[0] = cvt_pk(a0.x, a0.y); t8.u[1] = cvt_pk(a0.z, a0.w);
        t8.u[2] = cvt_pk(a1.x, a1.y); t8.u[3] = cvt_pk(a1.z, a1.w);
        *(uint4*)(As + row * 32 + sch) = t8.v;
      } else {
        *(short8*)(As + row * 32 + sch) =
            *(const short8*)((const unsigned short*)Ap + (size_t)(m0 + row) * 512 + k0 + gr * 8);
      }
    }
    // ---- stage B (128 rows x 32 k, f32 weights): 512 tasks
#pragma unroll
    for (int it = 0; it < 2; ++it) {
      const int idx = it * 256 + tid;
      const int row = idx >> 2, gr = idx & 3;
      const int sch = (gr ^ ((row >> 1) & 3)) << 3;
      const float4* src = (const float4*)(Bw + (size_t)(n0 + row) * 512 + k0 + gr * 8);
      const float4 b0 = src[0], b1 = src[1];
      U8 t8;
      t8.u[0] = cvt_pk(b0.x, b0.y); t8.u[1] = cvt_pk(b0.z, b0.w);
      t8.u[2] = cvt_pk(b1.x, b1.y); t8.u[3] = cvt_pk(b1.z, b1.w);
      *(uint4*)(Bs + row * 32 + sch) = t8.v;
    }
    __syncthreads();
    const short8 af = *(const short8*)(As + (wr + lr) * 32 + rch);
#pragma unroll
    for (int j = 0; j < 4; ++j) {
      const short8 bfr = *(const short8*)(Bs + (wc + j * 16 + lr) * 32 + rch);
      acc[j] = __builtin_amdgcn_mfma_f32_16x16x32_bf16(af, bfr, acc[j], 0, 0, 0);
    }
  }
#pragma unroll
  for (int j = 0; j < 4; ++j) {
    const int nn = n0 + wc + j * 16 + lr;
    const float bia = bias[nn];
    const int mm0 = m0 + wr + lc * 4;
    if (MODE == 0) {
      float* out = (float*)outp;
#pragma unroll
      for (int r = 0; r < 4; ++r)
        out[(size_t)(mm0 + r) * 512 + nn] = acc[j][r] + bia;
    } else {
      unsigned short* out = (unsigned short*)outp;
      const int b = mm0 >> 10, t0 = mm0 & 1023;
      const int h = nn >> 6, dk = nn & 63;
      U2 pk;
      pk.u[0] = cvt_pk(acc[j][0] + bia, acc[j][1] + bia);
      pk.u[1] = cvt_pk(acc[j][2] + bia, acc[j][3] + bia);
      *(uint2*)(out + (((size_t)((b * 8 + h) * 64 + dk)) << 10) + t0) = pk.v;
    }
  }
}

// ---------------- fused attention ----------------
// Block = 32 rows of one (b,h), 4 waves = 2 row-groups(16) x 2 j-halves(512).
// Grid 2048. LDS 24KB: vts [2 pair][2 dbuf][64dk][32j] swz, sks[1024], mks[32][128B] swz.
// sq/sk pre-scaled by log2(e): w = exp2(lrelu(sq_i+sk_j)) * maskbit.
__global__ LB void attn_kernel(const float* __restrict__ sq, const float* __restrict__ sk,
                               const unsigned char* __restrict__ mbits,
                               const unsigned short* __restrict__ vt,
                               unsigned short* __restrict__ xb) {
  __shared__ char smem[24576];
  unsigned short* vts = (unsigned short*)smem;   // 4 slabs x 2048 ush
  float* sks = (float*)(smem + 16384);           // [1024] f32
  char* mks = smem + 20480;                      // [32][128B]
  const int tid = threadIdx.x;
  const int w = tid >> 6, l = tid & 63;
  const int lr = l & 15, lc = l >> 4;
  const int bid = blockIdx.x;  // 2048: bh(64) x iblk(32)
  const int bh = bid >> 5, iblk = bid & 31;
  const int b = bh >> 3, h = bh & 7;
  const int i0b = iblk * 32;
  const int p = w >> 1, rgrp = w & 1;  // j-half, row-group
  const int j0p = p << 9;
  const float* sqp = sq + (size_t)bh * 1024;
  const float* skp = sk + (size_t)bh * 1024;
  const unsigned short* vtp = vt + ((size_t)bh << 16);
  const unsigned char* mrow = mbits + ((size_t)b << 17);

  // ---- prologue staging
  async_cp16(skp + (w << 8) + l * 4, sks + (w << 8));
  {
    const int row = (w << 3) + (l >> 3), c = l & 7;
    async_cp16(mrow + (size_t)(i0b + row) * 128 + ((c ^ (row & 7)) << 4), mks + (w << 10));
  }
  const int st_row0 = (rgrp << 5) + (l >> 2);
  const int st_row1 = st_row0 + 16;
  const unsigned short* sb0 = vtp + st_row0 * 1024 + j0p + (((l & 3) ^ ((st_row0 >> 1) & 3)) << 3);
  const unsigned short* sb1 = vtp + st_row1 * 1024 + j0p + (((l & 3) ^ ((st_row1 >> 1) & 3)) << 3);
  async_cp16(sb0, vts + ((p << 1) << 11) + (rgrp << 10));
  async_cp16(sb1, vts + ((p << 1) << 11) + (rgrp << 10) + 512);

  const float sq1 = sqp[i0b + (rgrp << 4) + lr];
  __syncthreads();

  f32x4 acc[4] = {};
  f32x4 accs = {};
  short8 ones;
#pragma unroll
  for (int t = 0; t < 8; ++t) ones[t] = (short)0x3f80;
  const int rowl = (rgrp << 4) + lr;
  const int mrowbase = rowl << 7;
  const int rxorb = (rowl & 7) << 4;
  const int vread = (lc ^ ((lr >> 1) & 3)) << 3;

  int cur = 0;
  for (int jt = 0; jt < 16; ++jt) {
    const int jb = jt << 5;
    if (jt < 15) {
      async_cp16(sb0 + jb + 32, vts + (((p << 1) | (cur ^ 1)) << 11) + (rgrp << 10));
      async_cp16(sb1 + jb + 32, vts + (((p << 1) | (cur ^ 1)) << 11) + (rgrp << 10) + 512);
    }
    const int q = (p << 6) + (jt << 2) + lc;
    const unsigned int mb = (unsigned char)mks[mrowbase + (q ^ rxorb)];
    const f32x4 s0 = *(const f32x4*)(sks + j0p + jb + (lc << 3));
    const f32x4 s1 = *(const f32x4*)(sks + j0p + jb + (lc << 3) + 4);
    float e[8];
#pragma unroll
    for (int t = 0; t < 8; ++t) {
      float s = sq1 + (t < 4 ? s0[t] : s1[t - 4]);
      s = fmaxf(s, 0.2f * s);
      const float ex = __builtin_amdgcn_exp2f(s);
      e[t] = (mb & (1u << t)) ? ex : 0.0f;
    }
    U8 pa;
    pa.u[0] = cvt_pk(e[0], e[1]); pa.u[1] = cvt_pk(e[2], e[3]);
    pa.u[2] = cvt_pk(e[4], e[5]); pa.u[3] = cvt_pk(e[6], e[7]);
    const unsigned short* vb_base = vts + (((p << 1) | cur) << 11) + vread;
#pragma unroll
    for (int c = 0; c < 4; ++c) {
      const short8 bv = *(const short8*)(vb_base + ((c << 4) + lr) * 32);
      acc[c] = __builtin_amdgcn_mfma_f32_16x16x32_bf16(pa.s, bv, acc[c], 0, 0, 0);
    }
    accs = __builtin_amdgcn_mfma_f32_16x16x32_bf16(pa.s, ones, accs, 0, 0, 0);
    __syncthreads();
    cur ^= 1;
  }

  // ---- 2-way j-half combine through LDS (vts region dead now)
  float* cb = (float*)smem;  // 2 x 64 lanes x 21 f32
  if (p == 1) {
    float* ptr = cb + (rgrp * 64 + l) * 21;
#pragma unroll
    for (int c = 0; c < 4; ++c)
#pragma unroll
      for (int r = 0; r < 4; ++r) ptr[c * 4 + r] = acc[c][r];
#pragma unroll
    for (int r = 0; r < 4; ++r) ptr[16 + r] = accs[r];
  }
  __syncthreads();
  if (p == 0) {
    const float* ptr = cb + (rgrp * 64 + l) * 21;
#pragma unroll
    for (int c = 0; c < 4; ++c)
#pragma unroll
      for (int r = 0; r < 4; ++r) acc[c][r] += ptr[c * 4 + r];
#pragma unroll
    for (int r = 0; r < 4; ++r) accs[r] += ptr[16 + r];
#pragma unroll
    for (int r = 0; r < 4; ++r) {
      const float s = accs[r];
      const float inv = s > 0.0f ? 1.0f / s : 0.0f;  // fully-masked row -> 0
      const int i = i0b + (rgrp << 4) + lc * 4 + r;
#pragma unroll
      for (int c = 0; c < 4; ++c)
        xb[(((size_t)(b * 1024 + i)) << 9) + h * 64 + c * 16 + lr] =
            f2bf(acc[c][r] * inv);
    }
  }
}

extern "C" void kernel_launch(void* const* d_in, const int* in_sizes, int n_in,
                              void* d_out, int out_size, void* d_ws, size_t ws_size,
                              hipStream_t stream) {
  const float* query = (const float*)d_in[0];
  const float* key   = (const float*)d_in[1];
  const float* value = (const float*)d_in[2];
  const int*   mask  = (const int*)d_in[3];
  const float* Wq = (const float*)d_in[4];
  const float* bq = (const float*)d_in[5];
  const float* Wk = (const float*)d_in[6];
  const float* bk = (const float*)d_in[7];
  const float* Wv = (const float*)d_in[8];
  const float* bv = (const float*)d_in[9];
  const float* Wo = (const float*)d_in[10];
  const float* bo = (const float*)d_in[11];
  const float* a  = (const float*)d_in[12];

  char* oc = (char*)d_out;
  unsigned short* vt = (unsigned short*)(oc + 0);
  unsigned int* mbits = (unsigned int*)(oc + 8388608);
  float* sqv = (float*)(oc + 9437184);
  float* skv = (float*)(oc + 9699328);
  unsigned short* Bfrag = (unsigned short*)(oc + 9961472);
  float* qkb = (float*)(oc + 9977856);
  unsigned short* xb = (unsigned short*)d_ws;

  prep_a_kernel<<<16, 256, 0, stream>>>(Wq, Wk, a, bq, bk, Bfrag, qkb);
  sqsk_kernel<<<512, 256, 0, stream>>>(query, key, Bfrag, qkb, sqv, skv);
  maskbits_kernel<<<32768, 256, 0, stream>>>(mask, mbits);
  gemm_bt<1, 1><<<1024, 256, 0, stream>>>((const void*)value, Wv, bv, (void*)vt);
  attn_kernel<<<2048, 256, 0, stream>>>(sqv, skv, (const unsigned char*)mbits, vt, xb);
  gemm_bt<0, 0><<<1024, 256, 0, stream>>>((const void*)xb, Wo, bo, d_out);
}

// Round 8
// 94.441 us; speedup vs baseline: 1.7183x; 1.1226x over previous
//
#include <hip/hip_runtime.h>
#include <hip/hip_bf16.h>
#include <stdint.h>

// B=8, N=1024, D=512, H=8, DK=64, ALPHA=0.2
//
// Scratch plan:
//   ws  : xb (attention output, bf16 [8192][512]) @ 0, 8,388,608 B.
//         wo16 @ 8,388,608 (512KB) IF ws_size >= 8,912,896 (else f32 fallback).
//   d_out (16,777,216 B f32) doubles as scratch (all write-before-read, dead
//   before the final GEMM overwrites):
//     vt    @ 0          8,388,608  (v^T per head: [b][h][dk][n] bf16)
//     mbit  @ 8,388,608  1,048,576  (mask bitset, [b][i][128B])
//     sq    @ 9,437,184    262,144  ([b][h][n] f32, pre-scaled by log2e)
//     sk    @ 9,699,328    262,144
//     Bfrag @ 9,961,472     16,384  (bf16 MFMA B-frags for sqsk)
//     qkb   @ 9,977,856         64
//     wv16  @10,485,760    524,288  (Wv bf16)
//     wo16f @11,010,048    524,288  (Wo bf16 fallback dst, unused read-side if !roomy)

typedef __attribute__((ext_vector_type(8))) short short8;
typedef __attribute__((ext_vector_type(4))) float f32x4;

#define LB __launch_bounds__(256)

union U8 { unsigned u[4]; short8 s; uint4 v; };
union U2 { unsigned u[2]; uint2 v; };

__device__ __forceinline__ unsigned short f2bf(float f) {
  unsigned int u = __float_as_uint(f);
  u += 0x7fffu + ((u >> 16) & 1u);
  return (unsigned short)(u >> 16);
}

// v_cvt_pk_bf16_f32: lo16 = bf16(a), hi16 = bf16(b), RNE (bit-identical to f2bf)
__device__ __forceinline__ unsigned cvt_pk(float a, float b) {
  unsigned r;
  asm("v_cvt_pk_bf16_f32 %0, %1, %2" : "=v"(r) : "v"(a), "v"(b));
  return r;
}

// async global->LDS, 16B per lane. lptr = wave-uniform base; gptr = per-lane.
__device__ __forceinline__ void async_cp16(const void* g, void* l) {
  __builtin_amdgcn_global_load_lds(
      (const __attribute__((address_space(1))) unsigned int*)g,
      (__attribute__((address_space(3))) unsigned int*)l, 16, 0, 0);
}

// ---------------- prep: weight bf16 casts + fold a into Wq/Wk -> Bfrag ----------------
// blocks 0-255: cast Wv -> wv16; 256-511: cast Wo -> wo16; 512-527: Bfrag/qkb.
__global__ LB void prep_kernel(const float* __restrict__ Wq, const float* __restrict__ Wk,
                               const float* __restrict__ a, const float* __restrict__ bq,
                               const float* __restrict__ bk,
                               unsigned short* __restrict__ Bfrag, float* __restrict__ qkb,
                               const float* __restrict__ Wv, const float* __restrict__ Wo,
                               unsigned short* __restrict__ wv16,
                               unsigned short* __restrict__ wo16) {
  const int blk = blockIdx.x;
  if (blk < 512) {
    const float* src = blk < 256 ? Wv : Wo;
    unsigned short* dst = blk < 256 ? wv16 : wo16;
    const int idx = ((blk & 255) * 256 + threadIdx.x) * 4;
    const float4 v = *(const float4*)(src + idx);
    U2 pk;
    pk.u[0] = cvt_pk(v.x, v.y);
    pk.u[1] = cvt_pk(v.z, v.w);
    *(uint2*)(dst + idx) = pk.v;
    return;
  }
  const int t = (blk - 512) * 256 + threadIdx.x;  // 4096 threads: d fast, h slow
  const int d = t & 511, h = t >> 9;
  float aq = 0.f, ak = 0.f;
#pragma unroll 4
  for (int dk = 0; dk < 64; ++dk) {
    aq += Wq[(size_t)(h * 64 + dk) * 512 + d] * a[h * 128 + dk];
    ak += Wk[(size_t)(h * 64 + dk) * 512 + d] * a[h * 128 + 64 + dk];
  }
  const float L2E = 1.4426950408889634f;
  const int ks = d >> 5, lch = (d >> 3) & 3, tt = d & 7;
  Bfrag[((ks * 64 + (lch << 4) + h) << 3) + tt] = f2bf(aq * L2E);
  Bfrag[((ks * 64 + (lch << 4) + 8 + h) << 3) + tt] = f2bf(ak * L2E);
  if (d == 0) {
    float s1 = 0.f, s2 = 0.f;
    for (int dk = 0; dk < 64; ++dk) {
      s1 += bq[h * 64 + dk] * a[h * 128 + dk];
      s2 += bk[h * 64 + dk] * a[h * 128 + 64 + dk];
    }
    qkb[h] = s1 * L2E;
    qkb[8 + h] = s2 * L2E;
  }
}

// ---------------- sq/sk via MFMA skinny GEMM ----------------
__global__ LB void sqsk_kernel(const float* __restrict__ query, const float* __restrict__ key,
                               const unsigned short* __restrict__ Bfrag,
                               const float* __restrict__ qkb,
                               float* __restrict__ sq, float* __restrict__ sk) {
  __shared__ float comb[3 * 64 * 9];
  const int tid = threadIdx.x, wv = tid >> 6, l = tid & 63;
  const int m0 = blockIdx.x * 16;
  const int k0 = wv * 128;
  short8 bf[4];
#pragma unroll
  for (int ks = 0; ks < 4; ++ks)
    bf[ks] = *(const short8*)(Bfrag + (((wv * 4 + ks) * 64 + l) << 3));
  const float* qbase = query + (size_t)(m0 + (l & 15)) * 512 + k0 + ((l >> 4) << 3);
  const float* kbase = key + (size_t)(m0 + (l & 15)) * 512 + k0 + ((l >> 4) << 3);
  f32x4 cq = {}, ck = {};
#pragma unroll
  for (int ks = 0; ks < 4; ++ks) {
    const float4 q0 = *(const float4*)(qbase + ks * 32);
    const float4 q1 = *(const float4*)(qbase + ks * 32 + 4);
    const float4 k0v = *(const float4*)(kbase + ks * 32);
    const float4 k1v = *(const float4*)(kbase + ks * 32 + 4);
    U8 aq, ak;
    aq.u[0] = cvt_pk(q0.x, q0.y); aq.u[1] = cvt_pk(q0.z, q0.w);
    aq.u[2] = cvt_pk(q1.x, q1.y); aq.u[3] = cvt_pk(q1.z, q1.w);
    ak.u[0] = cvt_pk(k0v.x, k0v.y); ak.u[1] = cvt_pk(k0v.z, k0v.w);
    ak.u[2] = cvt_pk(k1v.x, k1v.y); ak.u[3] = cvt_pk(k1v.z, k1v.w);
    cq = __builtin_amdgcn_mfma_f32_16x16x32_bf16(aq.s, bf[ks], cq, 0, 0, 0);
    ck = __builtin_amdgcn_mfma_f32_16x16x32_bf16(ak.s, bf[ks], ck, 0, 0, 0);
  }
  if (wv) {
    float* p = comb + ((wv - 1) * 64 + l) * 9;
#pragma unroll
    for (int r = 0; r < 4; ++r) { p[r] = cq[r]; p[4 + r] = ck[r]; }
  }
  __syncthreads();
  if (wv == 0) {
#pragma unroll
    for (int j = 0; j < 3; ++j) {
      const float* p = comb + (j * 64 + l) * 9;
#pragma unroll
      for (int r = 0; r < 4; ++r) { cq[r] += p[r]; ck[r] += p[4 + r]; }
    }
    const int col = l & 15;
    const int mbase = m0 + ((l >> 4) << 2);
    const int b = mbase >> 10;
    const float bia = qkb[col];
    if (col < 8) {
      float* out = sq + ((size_t)b * 8 + col) * 1024;
#pragma unroll
      for (int r = 0; r < 4; ++r) out[(mbase + r) & 1023] = cq[r] + bia;
    } else {
      float* out = sk + ((size_t)b * 8 + (col - 8)) * 1024;
#pragma unroll
      for (int r = 0; r < 4; ++r) out[(mbase + r) & 1023] = ck[r] + bia;
    }
  }
}

// ---------------- mask (B,N,N) int32 -> bitset ----------------
__global__ LB void maskbits_kernel(const int* __restrict__ mask,
                                   unsigned int* __restrict__ bits) {
  const size_t idx = (size_t)blockIdx.x * 256 + threadIdx.x;
  const unsigned long long bl = __ballot(mask[idx] != 0);
  if ((threadIdx.x & 63) == 0) {
    bits[idx >> 5] = (unsigned int)bl;
    bits[(idx >> 5) + 1] = (unsigned int)(bl >> 32);
  }
}

// ---------------- bf16 MFMA GEMM: C[8192][512] = A @ Bw[512][512]^T + bias
// 32x128 tiles, grid 1024. XOR-swizzled LDS. AB16/BB16: operand already bf16 ->
// stage via global_load_lds (no VALU); else f32 + cvt_pk staging.
// MODE 0: C -> fp32 row-major.  MODE 1: C -> bf16 v^T layout [b][h][dk][n].
template <int AB16, int BB16, int MODE>
__global__ LB void gemm_bt(const void* __restrict__ Ap,
                           const void* __restrict__ Bwp,
                           const float* __restrict__ bias, void* __restrict__ outp) {
  __shared__ unsigned short As[32 * 32];
  __shared__ unsigned short Bs[128 * 32];
  const int tid = threadIdx.x;
  const int w = tid >> 6, l = tid & 63;
  const int lr = l & 15, lc = l >> 4;
  const int bm = blockIdx.x >> 2, bn = blockIdx.x & 3;  // 256 x 4
  const int m0 = bm * 32, n0 = bn * 128;
  const int wr = (w & 1) * 16, wc = (w >> 1) * 64;
  const int rch = (lc ^ ((lr >> 1) & 3)) << 3;  // swizzled read chunk
  // cp16 source geometry (same swizzle identity for all 16-row groups)
  const int crow = l >> 2;                       // 0..15
  const int sc = (l & 3) ^ ((l >> 3) & 3);       // source chunk swizzle
  const unsigned short* a16 = (const unsigned short*)Ap;
  const unsigned short* b16 = (const unsigned short*)Bwp;
  const float* b32 = (const float*)Bwp;
  const unsigned short* bsrc0 = nullptr; const unsigned short* bsrc1 = nullptr;
  if (BB16) {
    bsrc0 = b16 + (size_t)(n0 + (w << 4) + crow) * 512 + (sc << 3);
    bsrc1 = b16 + (size_t)(n0 + ((w + 4) << 4) + crow) * 512 + (sc << 3);
  }
  const unsigned short* asrc = nullptr;
  if (AB16)
    asrc = a16 + (size_t)(m0 + ((w >> 1) << 4) + crow) * 512 + (sc << 3);

  f32x4 acc[4] = {};
  for (int kt = 0; kt < 16; ++kt) {
    const int k0 = kt * 32;
    if (kt) __syncthreads();
    // ---- stage A (32 rows x 32 k)
    if (AB16) {
      if (!(w & 1)) async_cp16(asrc + k0, As + ((w >> 1) << 9));
    } else {
      if (tid < 128) {
        const int row = tid >> 2, gr = tid & 3;
        const int sch = (gr ^ ((row >> 1) & 3)) << 3;
        const float4* src = (const float4*)((const float*)Ap + (size_t)(m0 + row) * 512 + k0 + gr * 8);
        const float4 a0 = src[0], a1 = src[1];
        U8 t8;
        t8.u[0] = cvt_pk(a0.x, a0.y); t8.u[1] = cvt_pk(a0.z, a0.w);
        t8.u[2] = cvt_pk(a1.x, a1.y); t8.u[3] = cvt_pk(a1.z, a1.w);
        *(uint4*)(As + row * 32 + sch) = t8.v;
      }
    }
    // ---- stage B (128 rows x 32 k)
    if (BB16) {
      async_cp16(bsrc0 + k0, Bs + (w << 9));
      async_cp16(bsrc1 + k0, Bs + ((w + 4) << 9));
    } else {
#pragma unroll
      for (int it = 0; it < 2; ++it) {
        const int idx = it * 256 + tid;
        const int row = idx >> 2, gr = idx & 3;
        const int sch = (gr ^ ((row >> 1) & 3)) << 3;
        const float4* src = (const float4*)(b32 + (size_t)(n0 + row) * 512 + k0 + gr * 8);
        const float4 b0 = src[0], b1 = src[1];
        U8 t8;
        t8.u[0] = cvt_pk(b0.x, b0.y); t8.u[1] = cvt_pk(b0.z, b0.w);
        t8.u[2] = cvt_pk(b1.x, b1.y); t8.u[3] = cvt_pk(b1.z, b1.w);
        *(uint4*)(Bs + row * 32 + sch) = t8.v;
      }
    }
    __syncthreads();
    const short8 af = *(const short8*)(As + (wr + lr) * 32 + rch);
#pragma unroll
    for (int j = 0; j < 4; ++j) {
      const short8 bfr = *(const short8*)(Bs + (wc + j * 16 + lr) * 32 + rch);
      acc[j] = __builtin_amdgcn_mfma_f32_16x16x32_bf16(af, bfr, acc[j], 0, 0, 0);
    }
  }
#pragma unroll
  for (int j = 0; j < 4; ++j) {
    const int nn = n0 + wc + j * 16 + lr;
    const float bia = bias[nn];
    const int mm0 = m0 + wr + lc * 4;
    if (MODE == 0) {
      float* out = (float*)outp;
#pragma unroll
      for (int r = 0; r < 4; ++r)
        out[(size_t)(mm0 + r) * 512 + nn] = acc[j][r] + bia;
    } else {
      unsigned short* out = (unsigned short*)outp;
      const int b = mm0 >> 10, t0 = mm0 & 1023;
      const int h = nn >> 6, dk = nn & 63;
      U2 pk;
      pk.u[0] = cvt_pk(acc[j][0] + bia, acc[j][1] + bia);
      pk.u[1] = cvt_pk(acc[j][2] + bia, acc[j][3] + bia);
      *(uint2*)(out + (((size_t)((b * 8 + h) * 64 + dk)) << 10) + t0) = pk.v;
    }
  }
}

// ---------------- fused attention: counted-vmcnt pipeline, raw barriers ----------------
// Block = 4 waves x 16 i-rows = 64 rows of one (b,h); full j per wave.
// Shared vt j-slab dbuf (2x4KB, chunk-swizzled), staged cooperatively (1 cp/wave/jt).
// Per jt: issue cp(jt+1); s_waitcnt vmcnt(1) (jt's slab done, jt+1 in flight);
// raw s_barrier; compute; raw s_barrier (release buffer). NO vmcnt(0) drains.
__global__ LB void attn_kernel(const float* __restrict__ sq, const float* __restrict__ sk,
                               const unsigned char* __restrict__ mbits,
                               const unsigned short* __restrict__ vt,
                               unsigned short* __restrict__ xb) {
  __shared__ char smem[20480];
  unsigned short* vts = (unsigned short*)smem;  // [2][64dk][32j] bf16, chunk-swizzled
  float* sks = (float*)(smem + 8192);           // [1024] f32
  char* mks = smem + 12288;                     // [64 rows][128B], byte-swizzled
  const int tid = threadIdx.x;
  const int w = tid >> 6, l = tid & 63;
  const int lr = l & 15, lc = l >> 4;
  const int bid = blockIdx.x;  // 1024 blocks: bh(64) x iblk(16); iblk fast
  const int bh = bid >> 4, iblk = bid & 15;
  const int b = bh >> 3, h = bh & 7;
  const int i0b = iblk * 64;
  const float* sqp = sq + (size_t)bh * 1024;
  const float* skp = sk + (size_t)bh * 1024;
  const unsigned short* vtp = vt + ((size_t)bh << 16);
  const unsigned char* mrow = mbits + ((size_t)b << 17);

  // ---- prologue staging (drained by the __syncthreads below)
  async_cp16(skp + (w << 8) + l * 4, sks + (w << 8));
#pragma unroll
  for (int m = 0; m < 2; ++m) {
    const int row = (w << 4) + (m << 3) + (l >> 3);
    const int c = (l & 7) ^ (row & 7);
    async_cp16(mrow + (size_t)(i0b + row) * 128 + (c << 4), mks + (w << 11) + (m << 10));
  }
  const int strow = (w << 4) + (l >> 2);
  const int stc = (l & 3) ^ ((strow >> 1) & 3);
  const unsigned short* srcw = vtp + strow * 1024 + (stc << 3);
  async_cp16(srcw, vts + (w << 9));  // jt=0 -> buf 0

  const int rowl = (w << 4) + lr;
  const float sq1 = sqp[i0b + rowl];
  __syncthreads();

  f32x4 acc[4] = {};
  f32x4 accs = {};
  short8 ones;
#pragma unroll
  for (int t = 0; t < 8; ++t) ones[t] = (short)0x3f80;  // bf16 1.0
  const int mrowbase = rowl << 7;
  const int rxorb = (rowl & 7) << 4;
  const int vread = (lc ^ ((lr >> 1) & 3)) << 3;

  int cur = 0;
  for (int jt = 0; jt < 32; ++jt) {
    if (jt < 31) {
      async_cp16(srcw + (jt + 1) * 32, vts + ((cur ^ 1) << 11) + (w << 9));
      asm volatile("s_waitcnt vmcnt(1)" ::: "memory");
    } else {
      asm volatile("s_waitcnt vmcnt(0)" ::: "memory");
    }
    __builtin_amdgcn_sched_barrier(0);
    __builtin_amdgcn_s_barrier();  // all waves' cp(jt) landed
    const int jb = jt << 5;
    const unsigned int mb = (unsigned char)mks[mrowbase + ((jt * 4 + lc) ^ rxorb)];
    const f32x4 s0 = *(const f32x4*)(sks + jb + (lc << 3));
    const f32x4 s1 = *(const f32x4*)(sks + jb + (lc << 3) + 4);
    float e[8];
#pragma unroll
    for (int t = 0; t < 8; ++t) {
      float s = sq1 + (t < 4 ? s0[t] : s1[t - 4]);
      s = fmaxf(s, 0.2f * s);  // leaky relu (positively homogeneous; log2e pre-folded)
      const float ex = __builtin_amdgcn_exp2f(s);
      e[t] = (mb & (1u << t)) ? ex : 0.0f;
    }
    U8 pa;
    pa.u[0] = cvt_pk(e[0], e[1]); pa.u[1] = cvt_pk(e[2], e[3]);
    pa.u[2] = cvt_pk(e[4], e[5]); pa.u[3] = cvt_pk(e[6], e[7]);
    const unsigned short* vb_base = vts + (cur << 11) + vread;
#pragma unroll
    for (int c = 0; c < 4; ++c) {
      const short8 bv = *(const short8*)(vb_base + ((c << 4) + lr) * 32);
      acc[c] = __builtin_amdgcn_mfma_f32_16x16x32_bf16(pa.s, bv, acc[c], 0, 0, 0);
    }
    accs = __builtin_amdgcn_mfma_f32_16x16x32_bf16(pa.s, ones, accs, 0, 0, 0);
    if (jt < 31) __builtin_amdgcn_s_barrier();  // all waves done reading buf[cur]
    cur ^= 1;
  }

#pragma unroll
  for (int r = 0; r < 4; ++r) {
    const float s = accs[r];
    const float inv = s > 0.0f ? 1.0f / s : 0.0f;  // fully-masked row -> 0
    const int i = i0b + (w << 4) + lc * 4 + r;
#pragma unroll
    for (int c = 0; c < 4; ++c)
      xb[(((size_t)(b * 1024 + i)) << 9) + h * 64 + c * 16 + lr] =
          f2bf(acc[c][r] * inv);
  }
}

extern "C" void kernel_launch(void* const* d_in, const int* in_sizes, int n_in,
                              void* d_out, int out_size, void* d_ws, size_t ws_size,
                              hipStream_t stream) {
  const float* query = (const float*)d_in[0];
  const float* key   = (const float*)d_in[1];
  const float* value = (const float*)d_in[2];
  const int*   mask  = (const int*)d_in[3];
  const float* Wq = (const float*)d_in[4];
  const float* bq = (const float*)d_in[5];
  const float* Wk = (const float*)d_in[6];
  const float* bk = (const float*)d_in[7];
  const float* Wv = (const float*)d_in[8];
  const float* bv = (const float*)d_in[9];
  const float* Wo = (const float*)d_in[10];
  const float* bo = (const float*)d_in[11];
  const float* a  = (const float*)d_in[12];

  char* oc = (char*)d_out;
  unsigned short* vt = (unsigned short*)(oc + 0);
  unsigned int* mbits = (unsigned int*)(oc + 8388608);
  float* sqv = (float*)(oc + 9437184);
  float* skv = (float*)(oc + 9699328);
  unsigned short* Bfrag = (unsigned short*)(oc + 9961472);
  float* qkb = (float*)(oc + 9977856);
  unsigned short* wv16 = (unsigned short*)(oc + 10485760);
  unsigned short* wo16f = (unsigned short*)(oc + 11010048);  // fallback dst
  unsigned short* xb = (unsigned short*)d_ws;

  const bool roomy = ws_size >= 8912896;  // xb + wo16 fit in ws
  unsigned short* wo16 = roomy ? (unsigned short*)((char*)d_ws + 8388608) : wo16f;

  prep_kernel<<<528, 256, 0, stream>>>(Wq, Wk, a, bq, bk, Bfrag, qkb, Wv, Wo, wv16, wo16);
  sqsk_kernel<<<512, 256, 0, stream>>>(query, key, Bfrag, qkb, sqv, skv);
  maskbits_kernel<<<32768, 256, 0, stream>>>(mask, mbits);
  gemm_bt<0, 1, 1><<<1024, 256, 0, stream>>>((const void*)value, (const void*)wv16, bv, (void*)vt);
  attn_kernel<<<1024, 256, 0, stream>>>(sqv, skv, (const unsigned char*)mbits, vt, xb);
  if (roomy)
    gemm_bt<1, 1, 0><<<1024, 256, 0, stream>>>((const void*)xb, (const void*)wo16, bo, d_out);
  else
    gemm_bt<1, 0, 0><<<1024, 256, 0, stream>>>((const void*)xb, (const void*)Wo, bo, d_out);
}

// Round 9
// 90.426 us; speedup vs baseline: 1.7946x; 1.0444x over previous
//
#include <hip/hip_runtime.h>
#include <hip/hip_bf16.h>
#include <stdint.h>

// B=8, N=1024, D=512, H=8, DK=64, ALPHA=0.2
//
// Scratch plan:
//   ws : [0..8.4MB) vb (value bf16) -> later reused as xb (attn out) after gemm_v
//        consumes vb; [8.4..8.9MB) wo16 IF ws_size >= 8,912,896 (else f32 fallback).
//   d_out doubles as scratch (write-before-read, dead before final GEMM):
//     vt    @ 0          8,388,608  (v^T per head: [b][h][dk][n] bf16)
//     mbit  @ 8,388,608  1,048,576  (mask bitset, [b][i][128B])
//     sq    @ 9,437,184    262,144  ([b][h][n] f32, pre-scaled by log2e)
//     sk    @ 9,699,328    262,144
//     Bfrag @ 9,961,472     16,384  (bf16 MFMA B-frags for sqsk)
//     qkb   @ 9,977,856         64
//     wv16  @10,485,760    524,288  (Wv bf16)
//     wo16f @11,010,048    524,288  (Wo bf16 fallback dst; only read if roomy==false -> never)

typedef __attribute__((ext_vector_type(8))) short short8;
typedef __attribute__((ext_vector_type(4))) float f32x4;

#define LB __launch_bounds__(256)

union U8 { unsigned u[4]; short8 s; uint4 v; };
union U2 { unsigned u[2]; uint2 v; };

__device__ __forceinline__ unsigned short f2bf(float f) {
  unsigned int u = __float_as_uint(f);
  u += 0x7fffu + ((u >> 16) & 1u);
  return (unsigned short)(u >> 16);
}

// v_cvt_pk_bf16_f32: lo16 = bf16(a), hi16 = bf16(b), RNE (bit-identical to f2bf)
__device__ __forceinline__ unsigned cvt_pk(float a, float b) {
  unsigned r;
  asm("v_cvt_pk_bf16_f32 %0, %1, %2" : "=v"(r) : "v"(a), "v"(b));
  return r;
}

// async global->LDS, 16B per lane. lptr = wave-uniform base; gptr = per-lane.
__device__ __forceinline__ void async_cp16(const void* g, void* l) {
  __builtin_amdgcn_global_load_lds(
      (const __attribute__((address_space(1))) unsigned int*)g,
      (__attribute__((address_space(3))) unsigned int*)l, 16, 0, 0);
}

// ---------------- mega-prep: maskbits + value/weight bf16 casts + Bfrag ----------------
// blocks [0,32768): mask->bits; [32768,36864): value->vb; [36864,37376): Wv/Wo casts;
// [37376,37392): fold a into Wq/Wk -> Bfrag/qkb.
__global__ LB void prep_kernel(const int* __restrict__ mask, unsigned int* __restrict__ bits,
                               const float* __restrict__ value, unsigned short* __restrict__ vb,
                               const float* __restrict__ Wv, const float* __restrict__ Wo,
                               unsigned short* __restrict__ wv16, unsigned short* __restrict__ wo16,
                               const float* __restrict__ Wq, const float* __restrict__ Wk,
                               const float* __restrict__ a, const float* __restrict__ bq,
                               const float* __restrict__ bk,
                               unsigned short* __restrict__ Bfrag, float* __restrict__ qkb) {
  const int blk = blockIdx.x;
  if (blk < 32768) {
    const size_t idx = (size_t)blk * 256 + threadIdx.x;
    const unsigned long long bl = __ballot(mask[idx] != 0);
    if ((threadIdx.x & 63) == 0) {
      bits[idx >> 5] = (unsigned int)bl;
      bits[(idx >> 5) + 1] = (unsigned int)(bl >> 32);
    }
    return;
  }
  if (blk < 36864) {
    const int idx = ((blk - 32768) * 256 + threadIdx.x) * 4;
    const float4 v = *(const float4*)(value + idx);
    U2 pk;
    pk.u[0] = cvt_pk(v.x, v.y);
    pk.u[1] = cvt_pk(v.z, v.w);
    *(uint2*)(vb + idx) = pk.v;
    return;
  }
  if (blk < 37376) {
    const int wblk = blk - 36864;
    const float* src = wblk < 256 ? Wv : Wo;
    unsigned short* dst = wblk < 256 ? wv16 : wo16;
    const int idx = ((wblk & 255) * 256 + threadIdx.x) * 4;
    const float4 v = *(const float4*)(src + idx);
    U2 pk;
    pk.u[0] = cvt_pk(v.x, v.y);
    pk.u[1] = cvt_pk(v.z, v.w);
    *(uint2*)(dst + idx) = pk.v;
    return;
  }
  const int t = (blk - 37376) * 256 + threadIdx.x;  // 4096 threads: d fast, h slow
  const int d = t & 511, h = t >> 9;
  float aq = 0.f, ak = 0.f;
#pragma unroll 4
  for (int dk = 0; dk < 64; ++dk) {
    aq += Wq[(size_t)(h * 64 + dk) * 512 + d] * a[h * 128 + dk];
    ak += Wk[(size_t)(h * 64 + dk) * 512 + d] * a[h * 128 + 64 + dk];
  }
  const float L2E = 1.4426950408889634f;
  const int ks = d >> 5, lch = (d >> 3) & 3, tt = d & 7;
  Bfrag[((ks * 64 + (lch << 4) + h) << 3) + tt] = f2bf(aq * L2E);
  Bfrag[((ks * 64 + (lch << 4) + 8 + h) << 3) + tt] = f2bf(ak * L2E);
  if (d == 0) {
    float s1 = 0.f, s2 = 0.f;
    for (int dk = 0; dk < 64; ++dk) {
      s1 += bq[h * 64 + dk] * a[h * 128 + dk];
      s2 += bk[h * 64 + dk] * a[h * 128 + 64 + dk];
    }
    qkb[h] = s1 * L2E;
    qkb[8 + h] = s2 * L2E;
  }
}

// ---------------- sq/sk via MFMA skinny GEMM ----------------
__global__ LB void sqsk_kernel(const float* __restrict__ query, const float* __restrict__ key,
                               const unsigned short* __restrict__ Bfrag,
                               const float* __restrict__ qkb,
                               float* __restrict__ sq, float* __restrict__ sk) {
  __shared__ float comb[3 * 64 * 9];
  const int tid = threadIdx.x, wv = tid >> 6, l = tid & 63;
  const int m0 = blockIdx.x * 16;
  const int k0 = wv * 128;
  short8 bf[4];
#pragma unroll
  for (int ks = 0; ks < 4; ++ks)
    bf[ks] = *(const short8*)(Bfrag + (((wv * 4 + ks) * 64 + l) << 3));
  const float* qbase = query + (size_t)(m0 + (l & 15)) * 512 + k0 + ((l >> 4) << 3);
  const float* kbase = key + (size_t)(m0 + (l & 15)) * 512 + k0 + ((l >> 4) << 3);
  f32x4 cq = {}, ck = {};
#pragma unroll
  for (int ks = 0; ks < 4; ++ks) {
    const float4 q0 = *(const float4*)(qbase + ks * 32);
    const float4 q1 = *(const float4*)(qbase + ks * 32 + 4);
    const float4 k0v = *(const float4*)(kbase + ks * 32);
    const float4 k1v = *(const float4*)(kbase + ks * 32 + 4);
    U8 aq, ak;
    aq.u[0] = cvt_pk(q0.x, q0.y); aq.u[1] = cvt_pk(q0.z, q0.w);
    aq.u[2] = cvt_pk(q1.x, q1.y); aq.u[3] = cvt_pk(q1.z, q1.w);
    ak.u[0] = cvt_pk(k0v.x, k0v.y); ak.u[1] = cvt_pk(k0v.z, k0v.w);
    ak.u[2] = cvt_pk(k1v.x, k1v.y); ak.u[3] = cvt_pk(k1v.z, k1v.w);
    cq = __builtin_amdgcn_mfma_f32_16x16x32_bf16(aq.s, bf[ks], cq, 0, 0, 0);
    ck = __builtin_amdgcn_mfma_f32_16x16x32_bf16(ak.s, bf[ks], ck, 0, 0, 0);
  }
  if (wv) {
    float* p = comb + ((wv - 1) * 64 + l) * 9;
#pragma unroll
    for (int r = 0; r < 4; ++r) { p[r] = cq[r]; p[4 + r] = ck[r]; }
  }
  __syncthreads();
  if (wv == 0) {
#pragma unroll
    for (int j = 0; j < 3; ++j) {
      const float* p = comb + (j * 64 + l) * 9;
#pragma unroll
      for (int r = 0; r < 4; ++r) { cq[r] += p[r]; ck[r] += p[4 + r]; }
    }
    const int col = l & 15;
    const int mbase = m0 + ((l >> 4) << 2);
    const int b = mbase >> 10;
    const float bia = qkb[col];
    if (col < 8) {
      float* out = sq + ((size_t)b * 8 + col) * 1024;
#pragma unroll
      for (int r = 0; r < 4; ++r) out[(mbase + r) & 1023] = cq[r] + bia;
    } else {
      float* out = sk + ((size_t)b * 8 + (col - 8)) * 1024;
#pragma unroll
      for (int r = 0; r < 4; ++r) out[(mbase + r) & 1023] = ck[r] + bia;
    }
  }
}

// ---------------- bf16 MFMA GEMM: C[8192][512] = A(bf16) @ Bw[512][512]^T + bias
// 32x128 tiles, grid 1024, XOR-swizzled LDS, double-buffered counted-vmcnt pipeline
// (BB16=1: uniform 3 global_load_lds per wave per kt, s_waitcnt vmcnt(3), raw barriers).
// BB16=0 fallback: B f32 + cvt staging with full drains.
// MODE 0: C -> fp32 row-major.  MODE 1: C -> bf16 v^T layout [b][h][dk][n].
template <int BB16, int MODE>
__global__ LB void gemm_bt(const unsigned short* __restrict__ A,
                           const void* __restrict__ Bwp,
                           const float* __restrict__ bias, void* __restrict__ outp) {
  __shared__ unsigned short As[2][32 * 32];
  __shared__ unsigned short Bs[2][128 * 32];
  const int tid = threadIdx.x;
  const int w = tid >> 6, l = tid & 63;
  const int lr = l & 15, lc = l >> 4;
  const int bm = blockIdx.x >> 2, bn = blockIdx.x & 3;  // 256 x 4
  const int m0 = bm * 32, n0 = bn * 128;
  const int wr = (w & 1) * 16, wc = (w >> 1) * 64;
  const int rch = (lc ^ ((lr >> 1) & 3)) << 3;  // swizzled read chunk
  // A staging: lanes 0-31 of each wave stage rows 8w..8w+7 (1 cp/wave)
  const int arow = (w << 3) + (l >> 2);
  const int asc = (l & 3) ^ ((arow >> 1) & 3);
  const unsigned short* asrc = A + (size_t)(m0 + arow) * 512 + (asc << 3);
  // B staging (bf16): 2 cps/wave, 16 rows each
  const int crow = l >> 2;
  const unsigned short* b16 = (const unsigned short*)Bwp;
  const float* b32 = (const float*)Bwp;
  const int brow0 = (w << 4) + crow, brow1 = ((w + 4) << 4) + crow;
  const unsigned short* bsrc0 = b16 + (size_t)(n0 + brow0) * 512 + (((l & 3) ^ ((brow0 >> 1) & 3)) << 3);
  const unsigned short* bsrc1 = b16 + (size_t)(n0 + brow1) * 512 + (((l & 3) ^ ((brow1 >> 1) & 3)) << 3);

  f32x4 acc[4] = {};
  if (BB16) {
    // prologue: stage kt=0 into buf 0
    if (l < 32) async_cp16(asrc, As[0] + (w << 8));
    async_cp16(bsrc0, Bs[0] + (w << 9));
    async_cp16(bsrc1, Bs[0] + ((w + 4) << 9));
    int buf = 0;
    for (int kt = 0; kt < 16; ++kt) {
      if (kt < 15) {
        const int k1 = (kt + 1) * 32;
        if (l < 32) async_cp16(asrc + k1, As[buf ^ 1] + (w << 8));
        async_cp16(bsrc0 + k1, Bs[buf ^ 1] + (w << 9));
        async_cp16(bsrc1 + k1, Bs[buf ^ 1] + ((w + 4) << 9));
        asm volatile("s_waitcnt vmcnt(3)" ::: "memory");
      } else {
        asm volatile("s_waitcnt vmcnt(0)" ::: "memory");
      }
      __builtin_amdgcn_sched_barrier(0);
      __builtin_amdgcn_s_barrier();
      const short8 af = *(const short8*)(As[buf] + (wr + lr) * 32 + rch);
      __builtin_amdgcn_s_setprio(1);
#pragma unroll
      for (int j = 0; j < 4; ++j) {
        const short8 bfr = *(const short8*)(Bs[buf] + (wc + j * 16 + lr) * 32 + rch);
        acc[j] = __builtin_amdgcn_mfma_f32_16x16x32_bf16(af, bfr, acc[j], 0, 0, 0);
      }
      __builtin_amdgcn_s_setprio(0);
      if (kt < 15) __builtin_amdgcn_s_barrier();
      buf ^= 1;
    }
  } else {
    // fallback: B f32 cvt staging, full drains (only used when ws too small)
    for (int kt = 0; kt < 16; ++kt) {
      const int k0 = kt * 32;
      if (kt) __syncthreads();
      if (l < 32) async_cp16(asrc + k0, As[0] + (w << 8));
#pragma unroll
      for (int it = 0; it < 2; ++it) {
        const int idx = it * 256 + tid;
        const int row = idx >> 2, gr = idx & 3;
        const int sch = (gr ^ ((row >> 1) & 3)) << 3;
        const float4* src = (const float4*)(b32 + (size_t)(n0 + row) * 512 + k0 + gr * 8);
        const float4 b0 = src[0], b1 = src[1];
        U8 t8;
        t8.u[0] = cvt_pk(b0.x, b0.y); t8.u[1] = cvt_pk(b0.z, b0.w);
        t8.u[2] = cvt_pk(b1.x, b1.y); t8.u[3] = cvt_pk(b1.z, b1.w);
        *(uint4*)(Bs[0] + row * 32 + sch) = t8.v;
      }
      __syncthreads();
      const short8 af = *(const short8*)(As[0] + (wr + lr) * 32 + rch);
#pragma unroll
      for (int j = 0; j < 4; ++j) {
        const short8 bfr = *(const short8*)(Bs[0] + (wc + j * 16 + lr) * 32 + rch);
        acc[j] = __builtin_amdgcn_mfma_f32_16x16x32_bf16(af, bfr, acc[j], 0, 0, 0);
      }
    }
  }
#pragma unroll
  for (int j = 0; j < 4; ++j) {
    const int nn = n0 + wc + j * 16 + lr;
    const float bia = bias[nn];
    const int mm0 = m0 + wr + lc * 4;
    if (MODE == 0) {
      float* out = (float*)outp;
#pragma unroll
      for (int r = 0; r < 4; ++r)
        out[(size_t)(mm0 + r) * 512 + nn] = acc[j][r] + bia;
    } else {
      unsigned short* out = (unsigned short*)outp;
      const int b = mm0 >> 10, t0 = mm0 & 1023;
      const int h = nn >> 6, dk = nn & 63;
      U2 pk;
      pk.u[0] = cvt_pk(acc[j][0] + bia, acc[j][1] + bia);
      pk.u[1] = cvt_pk(acc[j][2] + bia, acc[j][3] + bia);
      *(uint2*)(out + (((size_t)((b * 8 + h) * 64 + dk)) << 10) + t0) = pk.v;
    }
  }
}

// ---------------- fused attention: paired slabs, counted-vmcnt, raw barriers ----------------
// Block = 4 waves x 16 i-rows = 64 rows of one (b,h); full j per wave.
// 16 iterations x 64 j each; 2 sub-slabs per barrier pair; prefetch depth = 1 pair (2 cps).
// sq/sk pre-scaled by log2(e): w = exp2(lrelu(sq_i+sk_j)) * maskbit.
__global__ LB void attn_kernel(const float* __restrict__ sq, const float* __restrict__ sk,
                               const unsigned char* __restrict__ mbits,
                               const unsigned short* __restrict__ vt,
                               unsigned short* __restrict__ xb) {
  __shared__ char smem[28672];
  unsigned short* vts = (unsigned short*)smem;  // [2 pair][2 sub][64dk][32j] swz, 16KB
  float* sks = (float*)(smem + 16384);          // [1024] f32
  char* mks = smem + 20480;                     // [64 rows][128B], byte-swizzled
  const int tid = threadIdx.x;
  const int w = tid >> 6, l = tid & 63;
  const int lr = l & 15, lc = l >> 4;
  const int bid = blockIdx.x;  // 1024 blocks: bh(64) x iblk(16)
  const int bh = bid >> 4, iblk = bid & 15;
  const int b = bh >> 3, h = bh & 7;
  const int i0b = iblk * 64;
  const float* sqp = sq + (size_t)bh * 1024;
  const float* skp = sk + (size_t)bh * 1024;
  const unsigned short* vtp = vt + ((size_t)bh << 16);
  const unsigned char* mrow = mbits + ((size_t)b << 17);

  // ---- prologue staging (drained by the __syncthreads below)
  async_cp16(skp + (w << 8) + l * 4, sks + (w << 8));
#pragma unroll
  for (int m = 0; m < 2; ++m) {
    const int row = (w << 4) + (m << 3) + (l >> 3);
    const int c = (l & 7) ^ (row & 7);
    async_cp16(mrow + (size_t)(i0b + row) * 128 + (c << 4), mks + (w << 11) + (m << 10));
  }
  const int strow = (w << 4) + (l >> 2);
  const int stc = (l & 3) ^ ((strow >> 1) & 3);
  const unsigned short* srcw = vtp + strow * 1024 + (stc << 3);
  async_cp16(srcw, vts + (w << 9));          // slab 0 -> pair0 sub0
  async_cp16(srcw + 32, vts + 2048 + (w << 9));  // slab 1 -> pair0 sub1

  const int rowl = (w << 4) + lr;
  const float sq1 = sqp[i0b + rowl];
  __syncthreads();

  f32x4 acc[4] = {};
  f32x4 accs = {};
  short8 ones;
#pragma unroll
  for (int t = 0; t < 8; ++t) ones[t] = (short)0x3f80;  // bf16 1.0
  const int mrowbase = rowl << 7;
  const int rxorb = (rowl & 7) << 4;
  const int vread = (lc ^ ((lr >> 1) & 3)) << 3;

  int bufp = 0;
  for (int it = 0; it < 16; ++it) {
    if (it < 15) {
      const int sl = (it + 1) << 1;
      unsigned short* dst = vts + ((bufp ^ 1) << 12) + (w << 9);
      async_cp16(srcw + sl * 32, dst);
      async_cp16(srcw + sl * 32 + 32, dst + 2048);
      asm volatile("s_waitcnt vmcnt(2)" ::: "memory");
    } else {
      asm volatile("s_waitcnt vmcnt(0)" ::: "memory");
    }
    __builtin_amdgcn_sched_barrier(0);
    __builtin_amdgcn_s_barrier();  // pair(it) landed for all waves
#pragma unroll
    for (int sub = 0; sub < 2; ++sub) {
      const int jb = (it << 6) + (sub << 5);
      const unsigned int mb = (unsigned char)mks[mrowbase + (((jb >> 3) + lc) ^ rxorb)];
      const f32x4 s0 = *(const f32x4*)(sks + jb + (lc << 3));
      const f32x4 s1 = *(const f32x4*)(sks + jb + (lc << 3) + 4);
      float e[8];
#pragma unroll
      for (int t = 0; t < 8; ++t) {
        float s = sq1 + (t < 4 ? s0[t] : s1[t - 4]);
        s = fmaxf(s, 0.2f * s);  // leaky relu (positively homogeneous; log2e pre-folded)
        const float ex = __builtin_amdgcn_exp2f(s);
        e[t] = (mb & (1u << t)) ? ex : 0.0f;
      }
      U8 pa;
      pa.u[0] = cvt_pk(e[0], e[1]); pa.u[1] = cvt_pk(e[2], e[3]);
      pa.u[2] = cvt_pk(e[4], e[5]); pa.u[3] = cvt_pk(e[6], e[7]);
      const unsigned short* vb_base = vts + (bufp << 12) + (sub << 11) + vread;
      __builtin_amdgcn_s_setprio(1);
#pragma unroll
      for (int c = 0; c < 4; ++c) {
        const short8 bv = *(const short8*)(vb_base + ((c << 4) + lr) * 32);
        acc[c] = __builtin_amdgcn_mfma_f32_16x16x32_bf16(pa.s, bv, acc[c], 0, 0, 0);
      }
      accs = __builtin_amdgcn_mfma_f32_16x16x32_bf16(pa.s, ones, accs, 0, 0, 0);
      __builtin_amdgcn_s_setprio(0);
    }
    if (it < 15) __builtin_amdgcn_s_barrier();  // all waves done reading pair(it)
    bufp ^= 1;
  }

#pragma unroll
  for (int r = 0; r < 4; ++r) {
    const float s = accs[r];
    const float inv = s > 0.0f ? 1.0f / s : 0.0f;  // fully-masked row -> 0
    const int i = i0b + (w << 4) + lc * 4 + r;
#pragma unroll
    for (int c = 0; c < 4; ++c)
      xb[(((size_t)(b * 1024 + i)) << 9) + h * 64 + c * 16 + lr] =
          f2bf(acc[c][r] * inv);
  }
}

extern "C" void kernel_launch(void* const* d_in, const int* in_sizes, int n_in,
                              void* d_out, int out_size, void* d_ws, size_t ws_size,
                              hipStream_t stream) {
  const float* query = (const float*)d_in[0];
  const float* key   = (const float*)d_in[1];
  const float* value = (const float*)d_in[2];
  const int*   mask  = (const int*)d_in[3];
  const float* Wq = (const float*)d_in[4];
  const float* bq = (const float*)d_in[5];
  const float* Wk = (const float*)d_in[6];
  const float* bk = (const float*)d_in[7];
  const float* Wv = (const float*)d_in[8];
  const float* bv = (const float*)d_in[9];
  const float* Wo = (const float*)d_in[10];
  const float* bo = (const float*)d_in[11];
  const float* a  = (const float*)d_in[12];

  char* oc = (char*)d_out;
  unsigned short* vt = (unsigned short*)(oc + 0);
  unsigned int* mbits = (unsigned int*)(oc + 8388608);
  float* sqv = (float*)(oc + 9437184);
  float* skv = (float*)(oc + 9699328);
  unsigned short* Bfrag = (unsigned short*)(oc + 9961472);
  float* qkb = (float*)(oc + 9977856);
  unsigned short* wv16 = (unsigned short*)(oc + 10485760);
  unsigned short* wo16f = (unsigned short*)(oc + 11010048);  // fallback dst
  unsigned short* vb = (unsigned short*)d_ws;  // value bf16; dead after gemm_v
  unsigned short* xb = (unsigned short*)d_ws;  // attn out; same region, sequential use

  const bool roomy = ws_size >= 8912896;  // xb + wo16 fit in ws
  unsigned short* wo16 = roomy ? (unsigned short*)((char*)d_ws + 8388608) : wo16f;

  prep_kernel<<<37392, 256, 0, stream>>>(mask, mbits, value, vb, Wv, Wo, wv16, wo16,
                                         Wq, Wk, a, bq, bk, Bfrag, qkb);
  sqsk_kernel<<<512, 256, 0, stream>>>(query, key, Bfrag, qkb, sqv, skv);
  gemm_bt<1, 1><<<1024, 256, 0, stream>>>(vb, (const void*)wv16, bv, (void*)vt);
  attn_kernel<<<1024, 256, 0, stream>>>(sqv, skv, (const unsigned char*)mbits, vt, xb);
  if (roomy)
    gemm_bt<1, 0><<<1024, 256, 0, stream>>>(xb, (const void*)wo16, bo, d_out);
  else
    gemm_bt<0, 0><<<1024, 256, 0, stream>>>(xb, (const void*)Wo, bo, d_out);
}

// Round 10
// 82.147 us; speedup vs baseline: 1.9755x; 1.1008x over previous
//
#include <hip/hip_runtime.h>
#include <hip/hip_bf16.h>
#include <stdint.h>

// B=8, N=1024, D=512, H=8, DK=64, ALPHA=0.2
//
// Scratch plan:
//   ws : [0..8.4MB) vb (value bf16) -> reused as xb (attn out) after gemm_v
//        consumes vb; [8.4..8.9MB) wo16 IF ws_size >= 8,912,896 (else f32 fallback).
//   d_out doubles as scratch (write-before-read, dead before final GEMM):
//     vt    @ 0          8,388,608  (v^T per head: [b][h][dk][n] bf16)
//     mbit  @ 8,388,608  1,048,576  (mask bitset, [b][i][128B])
//     sq    @ 9,437,184    262,144  ([b][h][n] f32, pre-scaled by log2e)
//     sk    @ 9,699,328    262,144
//     Bfrag @ 9,961,472     16,384  (bf16 MFMA B-frags for sqsk)
//     qkb   @ 9,977,856         64
//     wv16  @10,485,760    524,288  (Wv bf16)
//     wo16f @11,010,048    524,288  (Wo bf16 fallback dst)

typedef __attribute__((ext_vector_type(8))) short short8;
typedef __attribute__((ext_vector_type(4))) float f32x4;

#define LB __launch_bounds__(256)

union U8 { unsigned u[4]; short8 s; uint4 v; };
union U2 { unsigned u[2]; uint2 v; };

__device__ __forceinline__ unsigned short f2bf(float f) {
  unsigned int u = __float_as_uint(f);
  u += 0x7fffu + ((u >> 16) & 1u);
  return (unsigned short)(u >> 16);
}

// v_cvt_pk_bf16_f32: lo16 = bf16(a), hi16 = bf16(b), RNE (bit-identical to f2bf)
__device__ __forceinline__ unsigned cvt_pk(float a, float b) {
  unsigned r;
  asm("v_cvt_pk_bf16_f32 %0, %1, %2" : "=v"(r) : "v"(a), "v"(b));
  return r;
}

// async global->LDS, 16B per lane. lptr = wave-uniform base; gptr = per-lane.
__device__ __forceinline__ void async_cp16(const void* g, void* l) {
  __builtin_amdgcn_global_load_lds(
      (const __attribute__((address_space(1))) unsigned int*)g,
      (__attribute__((address_space(3))) unsigned int*)l, 16, 0, 0);
}

// ---------------- mega-prep ----------------
// blocks [0,8192): mask int4 -> bitset (nibble pack via LDS);
// [8192,12288): value->vb bf16; [12288,12800): Wv/Wo casts; [12800,12816): Bfrag/qkb.
__global__ LB void prep_kernel(const int* __restrict__ mask, unsigned int* __restrict__ bits,
                               const float* __restrict__ value, unsigned short* __restrict__ vb,
                               const float* __restrict__ Wv, const float* __restrict__ Wo,
                               unsigned short* __restrict__ wv16, unsigned short* __restrict__ wo16,
                               const float* __restrict__ Wq, const float* __restrict__ Wk,
                               const float* __restrict__ a, const float* __restrict__ bq,
                               const float* __restrict__ bk,
                               unsigned short* __restrict__ Bfrag, float* __restrict__ qkb) {
  const int blk = blockIdx.x, tid = threadIdx.x;
  if (blk < 8192) {
    __shared__ unsigned char nb[256];
    const size_t e0 = ((size_t)blk * 256 + tid) * 4;
    const int4 m = *(const int4*)(mask + e0);
    nb[tid] = (unsigned char)((m.x != 0) | ((m.y != 0) << 1) | ((m.z != 0) << 2) | ((m.w != 0) << 3));
    __syncthreads();
    if (tid < 32) {
      const uint2 p = *(const uint2*)(nb + tid * 8);
      const unsigned lo = p.x, hi = p.y;
      const unsigned wl = (lo & 0xFu) | ((lo >> 4) & 0xF0u) | ((lo >> 8) & 0xF00u) | ((lo >> 12) & 0xF000u);
      const unsigned wh = (hi & 0xFu) | ((hi >> 4) & 0xF0u) | ((hi >> 8) & 0xF00u) | ((hi >> 12) & 0xF000u);
      bits[blk * 32 + tid] = wl | (wh << 16);
    }
    return;
  }
  if (blk < 12288) {
    const int idx = ((blk - 8192) * 256 + tid) * 4;
    const float4 v = *(const float4*)(value + idx);
    U2 pk;
    pk.u[0] = cvt_pk(v.x, v.y);
    pk.u[1] = cvt_pk(v.z, v.w);
    *(uint2*)(vb + idx) = pk.v;
    return;
  }
  if (blk < 12800) {
    const int wblk = blk - 12288;
    const float* src = wblk < 256 ? Wv : Wo;
    unsigned short* dst = wblk < 256 ? wv16 : wo16;
    const int idx = ((wblk & 255) * 256 + tid) * 4;
    const float4 v = *(const float4*)(src + idx);
    U2 pk;
    pk.u[0] = cvt_pk(v.x, v.y);
    pk.u[1] = cvt_pk(v.z, v.w);
    *(uint2*)(dst + idx) = pk.v;
    return;
  }
  const int t = (blk - 12800) * 256 + tid;  // 4096 threads: d fast, h slow
  const int d = t & 511, h = t >> 9;
  float aq = 0.f, ak = 0.f;
#pragma unroll 4
  for (int dk = 0; dk < 64; ++dk) {
    aq += Wq[(size_t)(h * 64 + dk) * 512 + d] * a[h * 128 + dk];
    ak += Wk[(size_t)(h * 64 + dk) * 512 + d] * a[h * 128 + 64 + dk];
  }
  const float L2E = 1.4426950408889634f;
  const int ks = d >> 5, lch = (d >> 3) & 3, tt = d & 7;
  Bfrag[((ks * 64 + (lch << 4) + h) << 3) + tt] = f2bf(aq * L2E);
  Bfrag[((ks * 64 + (lch << 4) + 8 + h) << 3) + tt] = f2bf(ak * L2E);
  if (d == 0) {
    float s1 = 0.f, s2 = 0.f;
    for (int dk = 0; dk < 64; ++dk) {
      s1 += bq[h * 64 + dk] * a[h * 128 + dk];
      s2 += bk[h * 64 + dk] * a[h * 128 + 64 + dk];
    }
    qkb[h] = s1 * L2E;
    qkb[8 + h] = s2 * L2E;
  }
}

// ---------------- merged: sqsk (blocks 0-511) + gemm_v MODE1 (blocks 512-1535) ----------
__global__ LB void sqsk_gemmv_kernel(const float* __restrict__ query, const float* __restrict__ key,
                                     const unsigned short* __restrict__ Bfrag,
                                     const float* __restrict__ qkb,
                                     float* __restrict__ sq, float* __restrict__ sk,
                                     const unsigned short* __restrict__ vbA,
                                     const unsigned short* __restrict__ wv16,
                                     const float* __restrict__ bvb,
                                     unsigned short* __restrict__ vt) {
  __shared__ char sm[20480];
  const int tid = threadIdx.x, w = tid >> 6, l = tid & 63;
  const int lr = l & 15, lc = l >> 4;
  if (blockIdx.x < 512) {
    // ---------- sqsk: rank-16 MFMA skinny GEMM ----------
    float* comb = (float*)sm;  // 3*64*9 f32 = 6912 B
    const int m0 = blockIdx.x * 16;
    const int k0 = w * 128;
    short8 bf[4];
#pragma unroll
    for (int ks = 0; ks < 4; ++ks)
      bf[ks] = *(const short8*)(Bfrag + (((w * 4 + ks) * 64 + l) << 3));
    const float* qbase = query + (size_t)(m0 + lr) * 512 + k0 + (lc << 3);
    const float* kbase = key + (size_t)(m0 + lr) * 512 + k0 + (lc << 3);
    f32x4 cq = {}, ck = {};
#pragma unroll
    for (int ks = 0; ks < 4; ++ks) {
      const float4 q0 = *(const float4*)(qbase + ks * 32);
      const float4 q1 = *(const float4*)(qbase + ks * 32 + 4);
      const float4 k0v = *(const float4*)(kbase + ks * 32);
      const float4 k1v = *(const float4*)(kbase + ks * 32 + 4);
      U8 aq, ak;
      aq.u[0] = cvt_pk(q0.x, q0.y); aq.u[1] = cvt_pk(q0.z, q0.w);
      aq.u[2] = cvt_pk(q1.x, q1.y); aq.u[3] = cvt_pk(q1.z, q1.w);
      ak.u[0] = cvt_pk(k0v.x, k0v.y); ak.u[1] = cvt_pk(k0v.z, k0v.w);
      ak.u[2] = cvt_pk(k1v.x, k1v.y); ak.u[3] = cvt_pk(k1v.z, k1v.w);
      cq = __builtin_amdgcn_mfma_f32_16x16x32_bf16(aq.s, bf[ks], cq, 0, 0, 0);
      ck = __builtin_amdgcn_mfma_f32_16x16x32_bf16(ak.s, bf[ks], ck, 0, 0, 0);
    }
    if (w) {
      float* p = comb + ((w - 1) * 64 + l) * 9;
#pragma unroll
      for (int r = 0; r < 4; ++r) { p[r] = cq[r]; p[4 + r] = ck[r]; }
    }
    __syncthreads();
    if (w == 0) {
#pragma unroll
      for (int j = 0; j < 3; ++j) {
        const float* p = comb + (j * 64 + l) * 9;
#pragma unroll
        for (int r = 0; r < 4; ++r) { cq[r] += p[r]; ck[r] += p[4 + r]; }
      }
      const int col = l & 15;
      const int mbase = m0 + (lc << 2);
      const int b = mbase >> 10;
      const float bia = qkb[col];
      if (col < 8) {
        float* out = sq + ((size_t)b * 8 + col) * 1024;
#pragma unroll
        for (int r = 0; r < 4; ++r) out[(mbase + r) & 1023] = cq[r] + bia;
      } else {
        float* out = sk + ((size_t)b * 8 + (col - 8)) * 1024;
#pragma unroll
        for (int r = 0; r < 4; ++r) out[(mbase + r) & 1023] = ck[r] + bia;
      }
    }
    return;
  }
  // ---------- gemm_v: vt = value @ Wv^T (32x128 tiles, dbuf counted-vmcnt) ----------
  unsigned short* As = (unsigned short*)sm;          // [2][1024]
  unsigned short* Bs = (unsigned short*)(sm + 4096); // [2][4096]
  const int bid = blockIdx.x - 512;
  const int bm = bid >> 2, bn = bid & 3;
  const int m0 = bm * 32, n0 = bn * 128;
  const int wr = (w & 1) * 16, wc = (w >> 1) * 64;
  const int rch = (lc ^ ((lr >> 1) & 3)) << 3;
  const int arow = (w << 3) + (l >> 2);
  const int asc = (l & 3) ^ ((arow >> 1) & 3);
  const unsigned short* asrc = vbA + (size_t)(m0 + arow) * 512 + (asc << 3);
  const int crow = l >> 2;
  const int brow0 = (w << 4) + crow, brow1 = ((w + 4) << 4) + crow;
  const unsigned short* bsrc0 = wv16 + (size_t)(n0 + brow0) * 512 + (((l & 3) ^ ((brow0 >> 1) & 3)) << 3);
  const unsigned short* bsrc1 = wv16 + (size_t)(n0 + brow1) * 512 + (((l & 3) ^ ((brow1 >> 1) & 3)) << 3);
  f32x4 acc[4] = {};
  if (l < 32) async_cp16(asrc, As + (w << 8));
  async_cp16(bsrc0, Bs + (w << 9));
  async_cp16(bsrc1, Bs + ((w + 4) << 9));
  int buf = 0;
  for (int kt = 0; kt < 16; ++kt) {
    if (kt < 15) {
      const int k1 = (kt + 1) * 32;
      if (l < 32) async_cp16(asrc + k1, As + ((buf ^ 1) << 10) + (w << 8));
      async_cp16(bsrc0 + k1, Bs + ((buf ^ 1) << 12) + (w << 9));
      async_cp16(bsrc1 + k1, Bs + ((buf ^ 1) << 12) + ((w + 4) << 9));
      asm volatile("s_waitcnt vmcnt(3)" ::: "memory");
    } else {
      asm volatile("s_waitcnt vmcnt(0)" ::: "memory");
    }
    __builtin_amdgcn_sched_barrier(0);
    __builtin_amdgcn_s_barrier();
    const short8 af = *(const short8*)(As + (buf << 10) + (wr + lr) * 32 + rch);
    __builtin_amdgcn_s_setprio(1);
#pragma unroll
    for (int j = 0; j < 4; ++j) {
      const short8 bfr = *(const short8*)(Bs + (buf << 12) + (wc + j * 16 + lr) * 32 + rch);
      acc[j] = __builtin_amdgcn_mfma_f32_16x16x32_bf16(af, bfr, acc[j], 0, 0, 0);
    }
    __builtin_amdgcn_s_setprio(0);
    if (kt < 15) __builtin_amdgcn_s_barrier();
    buf ^= 1;
  }
#pragma unroll
  for (int j = 0; j < 4; ++j) {
    const int nn = n0 + wc + j * 16 + lr;
    const float bia = bvb[nn];
    const int mm0 = m0 + wr + lc * 4;
    const int b = mm0 >> 10, t0 = mm0 & 1023;
    const int h = nn >> 6, dk = nn & 63;
    U2 pk;
    pk.u[0] = cvt_pk(acc[j][0] + bia, acc[j][1] + bia);
    pk.u[1] = cvt_pk(acc[j][2] + bia, acc[j][3] + bia);
    *(uint2*)(vt + (((size_t)((b * 8 + h) * 64 + dk)) << 10) + t0) = pk.v;
  }
}

// ---------------- bf16 MFMA GEMM (standalone, for gemm_o) ----------------
template <int BB16, int MODE>
__global__ LB void gemm_bt(const unsigned short* __restrict__ A,
                           const void* __restrict__ Bwp,
                           const float* __restrict__ bias, void* __restrict__ outp) {
  __shared__ unsigned short As[2][32 * 32];
  __shared__ unsigned short Bs[2][128 * 32];
  const int tid = threadIdx.x;
  const int w = tid >> 6, l = tid & 63;
  const int lr = l & 15, lc = l >> 4;
  const int bm = blockIdx.x >> 2, bn = blockIdx.x & 3;
  const int m0 = bm * 32, n0 = bn * 128;
  const int wr = (w & 1) * 16, wc = (w >> 1) * 64;
  const int rch = (lc ^ ((lr >> 1) & 3)) << 3;
  const int arow = (w << 3) + (l >> 2);
  const int asc = (l & 3) ^ ((arow >> 1) & 3);
  const unsigned short* asrc = A + (size_t)(m0 + arow) * 512 + (asc << 3);
  const int crow = l >> 2;
  const unsigned short* b16 = (const unsigned short*)Bwp;
  const float* b32 = (const float*)Bwp;
  const int brow0 = (w << 4) + crow, brow1 = ((w + 4) << 4) + crow;
  const unsigned short* bsrc0 = b16 + (size_t)(n0 + brow0) * 512 + (((l & 3) ^ ((brow0 >> 1) & 3)) << 3);
  const unsigned short* bsrc1 = b16 + (size_t)(n0 + brow1) * 512 + (((l & 3) ^ ((brow1 >> 1) & 3)) << 3);

  f32x4 acc[4] = {};
  if (BB16) {
    if (l < 32) async_cp16(asrc, As[0] + (w << 8));
    async_cp16(bsrc0, Bs[0] + (w << 9));
    async_cp16(bsrc1, Bs[0] + ((w + 4) << 9));
    int buf = 0;
    for (int kt = 0; kt < 16; ++kt) {
      if (kt < 15) {
        const int k1 = (kt + 1) * 32;
        if (l < 32) async_cp16(asrc + k1, As[buf ^ 1] + (w << 8));
        async_cp16(bsrc0 + k1, Bs[buf ^ 1] + (w << 9));
        async_cp16(bsrc1 + k1, Bs[buf ^ 1] + ((w + 4) << 9));
        asm volatile("s_waitcnt vmcnt(3)" ::: "memory");
      } else {
        asm volatile("s_waitcnt vmcnt(0)" ::: "memory");
      }
      __builtin_amdgcn_sched_barrier(0);
      __builtin_amdgcn_s_barrier();
      const short8 af = *(const short8*)(As[buf] + (wr + lr) * 32 + rch);
      __builtin_amdgcn_s_setprio(1);
#pragma unroll
      for (int j = 0; j < 4; ++j) {
        const short8 bfr = *(const short8*)(Bs[buf] + (wc + j * 16 + lr) * 32 + rch);
        acc[j] = __builtin_amdgcn_mfma_f32_16x16x32_bf16(af, bfr, acc[j], 0, 0, 0);
      }
      __builtin_amdgcn_s_setprio(0);
      if (kt < 15) __builtin_amdgcn_s_barrier();
      buf ^= 1;
    }
  } else {
    for (int kt = 0; kt < 16; ++kt) {
      const int k0 = kt * 32;
      if (kt) __syncthreads();
      if (l < 32) async_cp16(asrc + k0, As[0] + (w << 8));
#pragma unroll
      for (int it = 0; it < 2; ++it) {
        const int idx = it * 256 + tid;
        const int row = idx >> 2, gr = idx & 3;
        const int sch = (gr ^ ((row >> 1) & 3)) << 3;
        const float4* src = (const float4*)(b32 + (size_t)(n0 + row) * 512 + k0 + gr * 8);
        const float4 b0 = src[0], b1 = src[1];
        U8 t8;
        t8.u[0] = cvt_pk(b0.x, b0.y); t8.u[1] = cvt_pk(b0.z, b0.w);
        t8.u[2] = cvt_pk(b1.x, b1.y); t8.u[3] = cvt_pk(b1.z, b1.w);
        *(uint4*)(Bs[0] + row * 32 + sch) = t8.v;
      }
      __syncthreads();
      const short8 af = *(const short8*)(As[0] + (wr + lr) * 32 + rch);
#pragma unroll
      for (int j = 0; j < 4; ++j) {
        const short8 bfr = *(const short8*)(Bs[0] + (wc + j * 16 + lr) * 32 + rch);
        acc[j] = __builtin_amdgcn_mfma_f32_16x16x32_bf16(af, bfr, acc[j], 0, 0, 0);
      }
    }
  }
#pragma unroll
  for (int j = 0; j < 4; ++j) {
    const int nn = n0 + wc + j * 16 + lr;
    const float bia = bias[nn];
    const int mm0 = m0 + wr + lc * 4;
    if (MODE == 0) {
      float* out = (float*)outp;
#pragma unroll
      for (int r = 0; r < 4; ++r)
        out[(size_t)(mm0 + r) * 512 + nn] = acc[j][r] + bia;
    } else {
      unsigned short* out = (unsigned short*)outp;
      const int b = mm0 >> 10, t0 = mm0 & 1023;
      const int h = nn >> 6, dk = nn & 63;
      U2 pk;
      pk.u[0] = cvt_pk(acc[j][0] + bia, acc[j][1] + bia);
      pk.u[1] = cvt_pk(acc[j][2] + bia, acc[j][3] + bia);
      *(uint2*)(out + (((size_t)((b * 8 + h) * 64 + dk)) << 10) + t0) = pk.v;
    }
  }
}

// ---------------- fused attention: 128-row blocks, 2 row-tiles/wave ----------------
// Grid 512; bid mapping bh = bid&63 -> XCD (bid%8 == h) keeps each head's vt in one L2.
// Per iteration: stage 4 sub-slabs (128 j) into other buffer, vmcnt(4), barrier,
// compute 4 subs x {scores(2 row-tiles), 4 V-frags read ONCE, 10 MFMA}, barrier.
__global__ LB void attn_kernel(const float* __restrict__ sq, const float* __restrict__ sk,
                               const unsigned char* __restrict__ mbits,
                               const unsigned short* __restrict__ vt,
                               unsigned short* __restrict__ xb) {
  __shared__ char smem[53248];
  unsigned short* vts = (unsigned short*)smem;  // [2 buf][4 sub][64dk][32j] = 32KB
  float* sks = (float*)(smem + 32768);          // [1024] f32
  char* mks = smem + 36864;                     // [128 rows][128B], byte-swizzled
  const int tid = threadIdx.x;
  const int w = tid >> 6, l = tid & 63;
  const int lr = l & 15, lc = l >> 4;
  const int bid = blockIdx.x;  // 512: bh = bid&63 (XCD affinity), iblk = bid>>6
  const int bh = bid & 63, iblk = bid >> 6;
  const int b = bh >> 3, h = bh & 7;
  const int i0b = iblk << 7;
  const float* sqp = sq + (size_t)bh * 1024;
  const float* skp = sk + (size_t)bh * 1024;
  const unsigned short* vtp = vt + ((size_t)bh << 16);
  const unsigned char* mrow = mbits + ((size_t)b << 17);

  // ---- prologue staging (drained by __syncthreads)
  async_cp16(skp + (w << 8) + l * 4, sks + (w << 8));
#pragma unroll
  for (int m = 0; m < 4; ++m) {
    const int row = (w << 5) + (m << 3) + (l >> 3);
    const int c = (l & 7) ^ (row & 7);
    async_cp16(mrow + (size_t)(i0b + row) * 128 + (c << 4), mks + (w << 12) + (m << 10));
  }
  const int stl = l >> 2;                          // dk row within 16-group
  const int stc = (l & 3) ^ ((stl >> 1) & 3);      // swizzled source chunk
#define STAGE_VTS(tb, jb)                                                      \
  {                                                                            \
    unsigned short* dst = vts + ((tb) << 13) + (w << 11);                      \
    const unsigned short* s_ = vtp + stl * 1024 + (jb) + (w << 5) + (stc << 3);\
    async_cp16(s_, dst);                                                       \
    async_cp16(s_ + 16384, dst + 512);                                         \
    async_cp16(s_ + 32768, dst + 1024);                                        \
    async_cp16(s_ + 49152, dst + 1536);                                        \
  }
  STAGE_VTS(0, 0);
  float sq2[2];
#pragma unroll
  for (int g = 0; g < 2; ++g) sq2[g] = sqp[i0b + (w << 5) + (g << 4) + lr];
  __syncthreads();

  f32x4 acc[2][4] = {};
  f32x4 accs[2] = {};
  short8 ones;
#pragma unroll
  for (int t = 0; t < 8; ++t) ones[t] = (short)0x3f80;  // bf16 1.0
  const int vread = (lc ^ ((lr >> 1) & 3)) << 3;
  const int rx = (lr & 7) << 4;  // rowl&7 == lr&7 (w*32+g*16 ≡ 0 mod 8)

  int tb = 0;
  for (int it = 0; it < 8; ++it) {
    if (it < 7) {
      STAGE_VTS(tb ^ 1, (it + 1) << 7);
      asm volatile("s_waitcnt vmcnt(4)" ::: "memory");
    } else {
      asm volatile("s_waitcnt vmcnt(0)" ::: "memory");
    }
    __builtin_amdgcn_sched_barrier(0);
    __builtin_amdgcn_s_barrier();
#pragma unroll
    for (int s = 0; s < 4; ++s) {
      const int jb = (it << 7) + (s << 5);
      const int qb = (jb >> 3) + lc;
      const f32x4 s0 = *(const f32x4*)(sks + jb + (lc << 3));
      const f32x4 s1 = *(const f32x4*)(sks + jb + (lc << 3) + 4);
      U8 pa[2];
#pragma unroll
      for (int g = 0; g < 2; ++g) {
        const int rowl = (w << 5) + (g << 4) + lr;
        const unsigned mb = (unsigned char)mks[(rowl << 7) + (qb ^ rx)];
        const float sqv = sq2[g];
        float e[8];
#pragma unroll
        for (int t = 0; t < 8; ++t) {
          float sv = sqv + (t < 4 ? s0[t] : s1[t - 4]);
          sv = fmaxf(sv, 0.2f * sv);  // leaky relu (log2e pre-folded)
          const float ex = __builtin_amdgcn_exp2f(sv);
          e[t] = (mb & (1u << t)) ? ex : 0.0f;
        }
        pa[g].u[0] = cvt_pk(e[0], e[1]); pa[g].u[1] = cvt_pk(e[2], e[3]);
        pa[g].u[2] = cvt_pk(e[4], e[5]); pa[g].u[3] = cvt_pk(e[6], e[7]);
      }
      const unsigned short* vbb = vts + (tb << 13) + (s << 11) + vread;
      __builtin_amdgcn_s_setprio(1);
#pragma unroll
      for (int c = 0; c < 4; ++c) {
        const short8 bv = *(const short8*)(vbb + ((c << 4) + lr) * 32);
#pragma unroll
        for (int g = 0; g < 2; ++g)
          acc[g][c] = __builtin_amdgcn_mfma_f32_16x16x32_bf16(pa[g].s, bv, acc[g][c], 0, 0, 0);
      }
#pragma unroll
      for (int g = 0; g < 2; ++g)
        accs[g] = __builtin_amdgcn_mfma_f32_16x16x32_bf16(pa[g].s, ones, accs[g], 0, 0, 0);
      __builtin_amdgcn_s_setprio(0);
    }
    if (it < 7) __builtin_amdgcn_s_barrier();
    tb ^= 1;
  }
#undef STAGE_VTS

#pragma unroll
  for (int g = 0; g < 2; ++g) {
#pragma unroll
    for (int r = 0; r < 4; ++r) {
      const float sv = accs[g][r];
      const float inv = sv > 0.0f ? 1.0f / sv : 0.0f;  // fully-masked row -> 0
      const int i = i0b + (w << 5) + (g << 4) + (lc << 2) + r;
#pragma unroll
      for (int c = 0; c < 4; ++c)
        xb[(((size_t)(b * 1024 + i)) << 9) + h * 64 + (c << 4) + lr] =
            f2bf(acc[g][c][r] * inv);
    }
  }
}

extern "C" void kernel_launch(void* const* d_in, const int* in_sizes, int n_in,
                              void* d_out, int out_size, void* d_ws, size_t ws_size,
                              hipStream_t stream) {
  const float* query = (const float*)d_in[0];
  const float* key   = (const float*)d_in[1];
  const float* value = (const float*)d_in[2];
  const int*   mask  = (const int*)d_in[3];
  const float* Wq = (const float*)d_in[4];
  const float* bq = (const float*)d_in[5];
  const float* Wk = (const float*)d_in[6];
  const float* bk = (const float*)d_in[7];
  const float* Wv = (const float*)d_in[8];
  const float* bv = (const float*)d_in[9];
  const float* Wo = (const float*)d_in[10];
  const float* bo = (const float*)d_in[11];
  const float* a  = (const float*)d_in[12];

  char* oc = (char*)d_out;
  unsigned short* vt = (unsigned short*)(oc + 0);
  unsigned int* mbits = (unsigned int*)(oc + 8388608);
  float* sqv = (float*)(oc + 9437184);
  float* skv = (float*)(oc + 9699328);
  unsigned short* Bfrag = (unsigned short*)(oc + 9961472);
  float* qkb = (float*)(oc + 9977856);
  unsigned short* wv16 = (unsigned short*)(oc + 10485760);
  unsigned short* wo16f = (unsigned short*)(oc + 11010048);
  unsigned short* vb = (unsigned short*)d_ws;  // value bf16; dead after gemm_v
  unsigned short* xb = (unsigned short*)d_ws;  // attn out; same region, sequential use

  const bool roomy = ws_size >= 8912896;
  unsigned short* wo16 = roomy ? (unsigned short*)((char*)d_ws + 8388608) : wo16f;

  prep_kernel<<<12816, 256, 0, stream>>>(mask, mbits, value, vb, Wv, Wo, wv16, wo16,
                                         Wq, Wk, a, bq, bk, Bfrag, qkb);
  sqsk_gemmv_kernel<<<1536, 256, 0, stream>>>(query, key, Bfrag, qkb, sqv, skv,
                                              vb, wv16, bv, vt);
  attn_kernel<<<512, 256, 0, stream>>>(sqv, skv, (const unsigned char*)mbits, vt, xb);
  if (roomy)
    gemm_bt<1, 0><<<1024, 256, 0, stream>>>(xb, (const void*)wo16, bo, d_out);
  else
    gemm_bt<0, 0><<<1024, 256, 0, stream>>>(xb, (const void*)Wo, bo, d_out);
}

// Round 11
// 81.234 us; speedup vs baseline: 1.9977x; 1.0112x over previous
//
#include <hip/hip_runtime.h>
#include <hip/hip_bf16.h>
#include <stdint.h>

// B=8, N=1024, D=512, H=8, DK=64, ALPHA=0.2
//
// Scratch plan:
//   ws : [0..8.4MB) xb (attn out bf16); [8.4..8.9MB) wo16 IF ws_size >= 8,912,896.
//   d_out doubles as scratch (write-before-read, dead before final GEMM):
//     vt    @ 0          8,388,608  (v^T per head: [b][h][dk][n] bf16)
//     mbit  @ 8,388,608  1,048,576  (mask bitset, [b][i][128B])
//     sq    @ 9,437,184    262,144  ([b][h][n] f32, pre-scaled by log2e)
//     sk    @ 9,699,328    262,144
//     Bfrag @ 9,961,472     16,384  (bf16 MFMA B-frags for sqsk)
//     qkb   @ 9,977,856         64
//     wv16  @10,485,760    524,288  (Wv bf16)

typedef __attribute__((ext_vector_type(8))) short short8;
typedef __attribute__((ext_vector_type(4))) float f32x4;

#define LB __launch_bounds__(256)

union U8 { unsigned u[4]; short8 s; uint4 v; };
union U2 { unsigned u[2]; uint2 v; };

__device__ __forceinline__ unsigned short f2bf(float f) {
  unsigned int u = __float_as_uint(f);
  u += 0x7fffu + ((u >> 16) & 1u);
  return (unsigned short)(u >> 16);
}

// v_cvt_pk_bf16_f32: lo16 = bf16(a), hi16 = bf16(b), RNE (bit-identical to f2bf)
__device__ __forceinline__ unsigned cvt_pk(float a, float b) {
  unsigned r;
  asm("v_cvt_pk_bf16_f32 %0, %1, %2" : "=v"(r) : "v"(a), "v"(b));
  return r;
}

// async global->LDS, 16B per lane. lptr = wave-uniform base; gptr = per-lane.
__device__ __forceinline__ void async_cp16(const void* g, void* l) {
  __builtin_amdgcn_global_load_lds(
      (const __attribute__((address_space(1))) unsigned int*)g,
      (__attribute__((address_space(3))) unsigned int*)l, 16, 0, 0);
}

// ---------------- k1: weight casts + fold a into Wq/Wk -> Bfrag ----------------
// blocks 0-255: Wv->wv16; 256-511: Wo->wo16; 512-527: Bfrag/qkb.
__global__ LB void prep_kernel(const float* __restrict__ Wv, const float* __restrict__ Wo,
                               unsigned short* __restrict__ wv16, unsigned short* __restrict__ wo16,
                               const float* __restrict__ Wq, const float* __restrict__ Wk,
                               const float* __restrict__ a, const float* __restrict__ bq,
                               const float* __restrict__ bk,
                               unsigned short* __restrict__ Bfrag, float* __restrict__ qkb) {
  const int blk = blockIdx.x, tid = threadIdx.x;
  if (blk < 512) {
    const float* src = blk < 256 ? Wv : Wo;
    unsigned short* dst = blk < 256 ? wv16 : wo16;
    const int idx = ((blk & 255) * 256 + tid) * 4;
    const float4 v = *(const float4*)(src + idx);
    U2 pk;
    pk.u[0] = cvt_pk(v.x, v.y);
    pk.u[1] = cvt_pk(v.z, v.w);
    *(uint2*)(dst + idx) = pk.v;
    return;
  }
  const int t = (blk - 512) * 256 + tid;  // 4096 threads: d fast, h slow
  const int d = t & 511, h = t >> 9;
  float aq = 0.f, ak = 0.f;
#pragma unroll 4
  for (int dk = 0; dk < 64; ++dk) {
    aq += Wq[(size_t)(h * 64 + dk) * 512 + d] * a[h * 128 + dk];
    ak += Wk[(size_t)(h * 64 + dk) * 512 + d] * a[h * 128 + 64 + dk];
  }
  const float L2E = 1.4426950408889634f;
  const int ks = d >> 5, lch = (d >> 3) & 3, tt = d & 7;
  Bfrag[((ks * 64 + (lch << 4) + h) << 3) + tt] = f2bf(aq * L2E);
  Bfrag[((ks * 64 + (lch << 4) + 8 + h) << 3) + tt] = f2bf(ak * L2E);
  if (d == 0) {
    float s1 = 0.f, s2 = 0.f;
    for (int dk = 0; dk < 64; ++dk) {
      s1 += bq[h * 64 + dk] * a[h * 128 + dk];
      s2 += bk[h * 64 + dk] * a[h * 128 + 64 + dk];
    }
    qkb[h] = s1 * L2E;
    qkb[8 + h] = s2 * L2E;
  }
}

// ---------------- k2: gemm_v (0-1023) | sqsk (1024-1535) | maskbits (1536-9727) ------
// gemm_v stages A directly from f32 value: reg load -> cvt_pk -> ds_write_b64, inside
// the counted-vmcnt dbuf pipeline (no separate cast pass). B = wv16 via global_load_lds.
__global__ LB void mid_kernel(const float* __restrict__ query, const float* __restrict__ key,
                              const unsigned short* __restrict__ Bfrag,
                              const float* __restrict__ qkb,
                              float* __restrict__ sq, float* __restrict__ sk,
                              const float* __restrict__ value,
                              const unsigned short* __restrict__ wv16,
                              const float* __restrict__ bvb, unsigned short* __restrict__ vt,
                              const int* __restrict__ mask, unsigned int* __restrict__ bits) {
  __shared__ char sm[20480];
  const int tid = threadIdx.x, w = tid >> 6, l = tid & 63;
  const int lr = l & 15, lc = l >> 4;
  const int bid = blockIdx.x;
  if (bid >= 1536) {
    // ---------- maskbits: int4 load + nibble pack via LDS ----------
    unsigned char* nb = (unsigned char*)sm;
    const size_t e0 = ((size_t)(bid - 1536) * 256 + tid) * 4;
    const int4 m = *(const int4*)(mask + e0);
    nb[tid] = (unsigned char)((m.x != 0) | ((m.y != 0) << 1) | ((m.z != 0) << 2) | ((m.w != 0) << 3));
    __syncthreads();
    if (tid < 32) {
      const uint2 p = *(const uint2*)(nb + tid * 8);
      const unsigned lo = p.x, hi = p.y;
      const unsigned wl = (lo & 0xFu) | ((lo >> 4) & 0xF0u) | ((lo >> 8) & 0xF00u) | ((lo >> 12) & 0xF000u);
      const unsigned wh = (hi & 0xFu) | ((hi >> 4) & 0xF0u) | ((hi >> 8) & 0xF00u) | ((hi >> 12) & 0xF000u);
      bits[(bid - 1536) * 32 + tid] = wl | (wh << 16);
    }
    return;
  }
  if (bid >= 1024) {
    // ---------- sqsk: rank-16 MFMA skinny GEMM ----------
    float* comb = (float*)sm;  // 3*64*9 f32
    const int m0 = (bid - 1024) * 16;
    const int k0 = w * 128;
    short8 bf[4];
#pragma unroll
    for (int ks = 0; ks < 4; ++ks)
      bf[ks] = *(const short8*)(Bfrag + (((w * 4 + ks) * 64 + l) << 3));
    const float* qbase = query + (size_t)(m0 + lr) * 512 + k0 + (lc << 3);
    const float* kbase = key + (size_t)(m0 + lr) * 512 + k0 + (lc << 3);
    f32x4 cq = {}, ck = {};
#pragma unroll
    for (int ks = 0; ks < 4; ++ks) {
      const float4 q0 = *(const float4*)(qbase + ks * 32);
      const float4 q1 = *(const float4*)(qbase + ks * 32 + 4);
      const float4 k0v = *(const float4*)(kbase + ks * 32);
      const float4 k1v = *(const float4*)(kbase + ks * 32 + 4);
      U8 aq, ak;
      aq.u[0] = cvt_pk(q0.x, q0.y); aq.u[1] = cvt_pk(q0.z, q0.w);
      aq.u[2] = cvt_pk(q1.x, q1.y); aq.u[3] = cvt_pk(q1.z, q1.w);
      ak.u[0] = cvt_pk(k0v.x, k0v.y); ak.u[1] = cvt_pk(k0v.z, k0v.w);
      ak.u[2] = cvt_pk(k1v.x, k1v.y); ak.u[3] = cvt_pk(k1v.z, k1v.w);
      cq = __builtin_amdgcn_mfma_f32_16x16x32_bf16(aq.s, bf[ks], cq, 0, 0, 0);
      ck = __builtin_amdgcn_mfma_f32_16x16x32_bf16(ak.s, bf[ks], ck, 0, 0, 0);
    }
    if (w) {
      float* p = comb + ((w - 1) * 64 + l) * 9;
#pragma unroll
      for (int r = 0; r < 4; ++r) { p[r] = cq[r]; p[4 + r] = ck[r]; }
    }
    __syncthreads();
    if (w == 0) {
#pragma unroll
      for (int j = 0; j < 3; ++j) {
        const float* p = comb + (j * 64 + l) * 9;
#pragma unroll
        for (int r = 0; r < 4; ++r) { cq[r] += p[r]; ck[r] += p[4 + r]; }
      }
      const int col = l & 15;
      const int mbase = m0 + (lc << 2);
      const int b = mbase >> 10;
      const float bia = qkb[col];
      if (col < 8) {
        float* out = sq + ((size_t)b * 8 + col) * 1024;
#pragma unroll
        for (int r = 0; r < 4; ++r) out[(mbase + r) & 1023] = cq[r] + bia;
      } else {
        float* out = sk + ((size_t)b * 8 + (col - 8)) * 1024;
#pragma unroll
        for (int r = 0; r < 4; ++r) out[(mbase + r) & 1023] = ck[r] + bia;
      }
    }
    return;
  }
  // ---------- gemm_v: vt = value @ Wv^T, A f32 reg-staged, dbuf counted-vmcnt ----------
  unsigned short* As = (unsigned short*)sm;          // [2][32*32]
  unsigned short* Bs = (unsigned short*)(sm + 4096); // [2][128*32]
  const int bm = bid >> 2, bn = bid & 3;
  const int m0 = bm * 32, n0 = bn * 128;
  const int wr = (w & 1) * 16, wc = (w >> 1) * 64;
  const int rch = (lc ^ ((lr >> 1) & 3)) << 3;
  // A: 8 rows/wave, lane = (row l>>3, 4-f32 chunk l&7)
  const int arow = (w << 3) + (l >> 3);
  const int akc = l & 7;
  const float* asrc = value + (size_t)(m0 + arow) * 512 + (akc << 2);
  const int ach = ((akc >> 1) ^ ((arow >> 1) & 3));
  const int aoff = arow * 32 + (ach << 3) + ((akc & 1) << 2);  // ushort offset
  // B: 2 glds/wave
  const int crow = l >> 2;
  const int brow0 = (w << 4) + crow, brow1 = ((w + 4) << 4) + crow;
  const unsigned short* bsrc0 = wv16 + (size_t)(n0 + brow0) * 512 + (((l & 3) ^ ((brow0 >> 1) & 3)) << 3);
  const unsigned short* bsrc1 = wv16 + (size_t)(n0 + brow1) * 512 + (((l & 3) ^ ((brow1 >> 1) & 3)) << 3);

  f32x4 acc[4] = {};
  // prologue: kt=0
  float4 areg = *(const float4*)(asrc);
  async_cp16(bsrc0, Bs + (w << 9));
  async_cp16(bsrc1, Bs + ((w + 4) << 9));
  {
    U2 aw;
    aw.u[0] = cvt_pk(areg.x, areg.y);
    aw.u[1] = cvt_pk(areg.z, areg.w);
    *(uint2*)(As + aoff) = aw.v;
  }
  areg = *(const float4*)(asrc + 32);
  async_cp16(bsrc0 + 32, Bs + 4096 + (w << 9));
  async_cp16(bsrc1 + 32, Bs + 4096 + ((w + 4) << 9));
  asm volatile("s_waitcnt vmcnt(3)" ::: "memory");  // B(0) landed; kt=1's 3 in flight
  asm volatile("s_waitcnt lgkmcnt(0)" ::: "memory");
  __builtin_amdgcn_sched_barrier(0);
  __builtin_amdgcn_s_barrier();
  int buf = 0;
  for (int kt = 0; kt < 16; ++kt) {
    const short8 af = *(const short8*)(As + (buf << 10) + (wr + lr) * 32 + rch);
    __builtin_amdgcn_s_setprio(1);
#pragma unroll
    for (int j = 0; j < 4; ++j) {
      const short8 bfr = *(const short8*)(Bs + (buf << 12) + (wc + j * 16 + lr) * 32 + rch);
      acc[j] = __builtin_amdgcn_mfma_f32_16x16x32_bf16(af, bfr, acc[j], 0, 0, 0);
    }
    __builtin_amdgcn_s_setprio(0);
    __builtin_amdgcn_s_barrier();  // release buf
    if (kt < 15) {
      // areg holds A(kt+1) (compiler waits its vmcnt before cvt)
      U2 aw;
      aw.u[0] = cvt_pk(areg.x, areg.y);
      aw.u[1] = cvt_pk(areg.z, areg.w);
      *(uint2*)(As + ((buf ^ 1) << 10) + aoff) = aw.v;
      if (kt < 14) {
        areg = *(const float4*)(asrc + (kt + 2) * 32);
        async_cp16(bsrc0 + (kt + 2) * 32, Bs + (buf << 12) + (w << 9));
        async_cp16(bsrc1 + (kt + 2) * 32, Bs + (buf << 12) + ((w + 4) << 9));
        asm volatile("s_waitcnt vmcnt(3)" ::: "memory");  // B(kt+1) landed
      } else {
        asm volatile("s_waitcnt vmcnt(0)" ::: "memory");
      }
      asm volatile("s_waitcnt lgkmcnt(0)" ::: "memory");
      __builtin_amdgcn_sched_barrier(0);
      __builtin_amdgcn_s_barrier();  // acquire kt+1
    }
    buf ^= 1;
  }
#pragma unroll
  for (int j = 0; j < 4; ++j) {
    const int nn = n0 + wc + j * 16 + lr;
    const float bia = bvb[nn];
    const int mm0 = m0 + wr + lc * 4;
    const int b = mm0 >> 10, t0 = mm0 & 1023;
    const int h = nn >> 6, dk = nn & 63;
    U2 pk;
    pk.u[0] = cvt_pk(acc[j][0] + bia, acc[j][1] + bia);
    pk.u[1] = cvt_pk(acc[j][2] + bia, acc[j][3] + bia);
    *(uint2*)(vt + (((size_t)((b * 8 + h) * 64 + dk)) << 10) + t0) = pk.v;
  }
}

// ---------------- k4: bf16 MFMA GEMM (gemm_o) ----------------
template <int BB16>
__global__ LB void gemm_bt(const unsigned short* __restrict__ A,
                           const void* __restrict__ Bwp,
                           const float* __restrict__ bias, float* __restrict__ outp) {
  __shared__ unsigned short As[2][32 * 32];
  __shared__ unsigned short Bs[2][128 * 32];
  const int tid = threadIdx.x;
  const int w = tid >> 6, l = tid & 63;
  const int lr = l & 15, lc = l >> 4;
  const int bm = blockIdx.x >> 2, bn = blockIdx.x & 3;
  const int m0 = bm * 32, n0 = bn * 128;
  const int wr = (w & 1) * 16, wc = (w >> 1) * 64;
  const int rch = (lc ^ ((lr >> 1) & 3)) << 3;
  const int arow = (w << 3) + (l >> 2);
  const int asc = (l & 3) ^ ((arow >> 1) & 3);
  const unsigned short* asrc = A + (size_t)(m0 + arow) * 512 + (asc << 3);
  const int crow = l >> 2;
  const unsigned short* b16 = (const unsigned short*)Bwp;
  const float* b32 = (const float*)Bwp;
  const int brow0 = (w << 4) + crow, brow1 = ((w + 4) << 4) + crow;
  const unsigned short* bsrc0 = b16 + (size_t)(n0 + brow0) * 512 + (((l & 3) ^ ((brow0 >> 1) & 3)) << 3);
  const unsigned short* bsrc1 = b16 + (size_t)(n0 + brow1) * 512 + (((l & 3) ^ ((brow1 >> 1) & 3)) << 3);

  f32x4 acc[4] = {};
  if (BB16) {
    if (l < 32) async_cp16(asrc, As[0] + (w << 8));
    async_cp16(bsrc0, Bs[0] + (w << 9));
    async_cp16(bsrc1, Bs[0] + ((w + 4) << 9));
    int buf = 0;
    for (int kt = 0; kt < 16; ++kt) {
      if (kt < 15) {
        const int k1 = (kt + 1) * 32;
        if (l < 32) async_cp16(asrc + k1, As[buf ^ 1] + (w << 8));
        async_cp16(bsrc0 + k1, Bs[buf ^ 1] + (w << 9));
        async_cp16(bsrc1 + k1, Bs[buf ^ 1] + ((w + 4) << 9));
        asm volatile("s_waitcnt vmcnt(3)" ::: "memory");
      } else {
        asm volatile("s_waitcnt vmcnt(0)" ::: "memory");
      }
      __builtin_amdgcn_sched_barrier(0);
      __builtin_amdgcn_s_barrier();
      const short8 af = *(const short8*)(As[buf] + (wr + lr) * 32 + rch);
      __builtin_amdgcn_s_setprio(1);
#pragma unroll
      for (int j = 0; j < 4; ++j) {
        const short8 bfr = *(const short8*)(Bs[buf] + (wc + j * 16 + lr) * 32 + rch);
        acc[j] = __builtin_amdgcn_mfma_f32_16x16x32_bf16(af, bfr, acc[j], 0, 0, 0);
      }
      __builtin_amdgcn_s_setprio(0);
      if (kt < 15) __builtin_amdgcn_s_barrier();
      buf ^= 1;
    }
  } else {
    for (int kt = 0; kt < 16; ++kt) {
      const int k0 = kt * 32;
      if (kt) __syncthreads();
      if (l < 32) async_cp16(asrc + k0, As[0] + (w << 8));
#pragma unroll
      for (int it = 0; it < 2; ++it) {
        const int idx = it * 256 + tid;
        const int row = idx >> 2, gr = idx & 3;
        const int sch = (gr ^ ((row >> 1) & 3)) << 3;
        const float4* src = (const float4*)(b32 + (size_t)(n0 + row) * 512 + k0 + gr * 8);
        const float4 b0 = src[0], b1 = src[1];
        U8 t8;
        t8.u[0] = cvt_pk(b0.x, b0.y); t8.u[1] = cvt_pk(b0.z, b0.w);
        t8.u[2] = cvt_pk(b1.x, b1.y); t8.u[3] = cvt_pk(b1.z, b1.w);
        *(uint4*)(Bs[0] + row * 32 + sch) = t8.v;
      }
      __syncthreads();
      const short8 af = *(const short8*)(As[0] + (wr + lr) * 32 + rch);
#pragma unroll
      for (int j = 0; j < 4; ++j) {
        const short8 bfr = *(const short8*)(Bs[0] + (wc + j * 16 + lr) * 32 + rch);
        acc[j] = __builtin_amdgcn_mfma_f32_16x16x32_bf16(af, bfr, acc[j], 0, 0, 0);
      }
    }
  }
#pragma unroll
  for (int j = 0; j < 4; ++j) {
    const int nn = n0 + wc + j * 16 + lr;
    const float bia = bias[nn];
    const int mm0 = m0 + wr + lc * 4;
#pragma unroll
    for (int r = 0; r < 4; ++r)
      outp[(size_t)(mm0 + r) * 512 + nn] = acc[j][r] + bia;
  }
}

// ---------------- k3: fused attention, j-split, barrier-free main loop ----------------
// Block = 128 rows of one (b,h); 4 waves: w&1 = row-half (64 rows, 4 tiles),
// w>>1 = j-half (512 j). Each wave stages its OWN V slab (private dbuf) -> no loop
// barriers; self-paced vmcnt(4). 2-way j-combine via LDS (pad-84) at the end.
__global__ LB void attn_kernel(const float* __restrict__ sq, const float* __restrict__ sk,
                               const unsigned char* __restrict__ mbits,
                               const unsigned short* __restrict__ vt,
                               unsigned short* __restrict__ xb) {
  __shared__ char smem[53248];
  unsigned short* vts = (unsigned short*)smem;  // [4 wave][2 buf][64dk][32j] = 32KB
  float* sks = (float*)(smem + 32768);          // [1024] f32
  char* mks = smem + 36864;                     // [128 rows][128B], byte-swizzled
  const int tid = threadIdx.x;
  const int w = tid >> 6, l = tid & 63;
  const int lr = l & 15, lc = l >> 4;
  const int bid = blockIdx.x;  // 512: bh = bid&63 (XCD affinity: bid%8==h), iblk = bid>>6
  const int bh = bid & 63, iblk = bid >> 6;
  const int b = bh >> 3, h = bh & 7;
  const int i0b = iblk << 7;
  const int rh = w & 1, jh = w >> 1;
  const int j0 = jh << 9;
  const float* sqp = sq + (size_t)bh * 1024;
  const float* skp = sk + (size_t)bh * 1024;
  const unsigned short* vtp = vt + ((size_t)bh << 16);
  const unsigned char* mrow = mbits + ((size_t)b << 17);

  // ---- prologue staging (drained by __syncthreads)
  async_cp16(skp + (w << 8) + l * 4, sks + (w << 8));
#pragma unroll
  for (int m = 0; m < 4; ++m) {
    const int row = (w << 5) + (m << 3) + (l >> 3);
    const int c = (l & 7) ^ (row & 7);
    async_cp16(mrow + (size_t)(i0b + row) * 128 + (c << 4), mks + (w << 12) + (m << 10));
  }
  const int stl = l >> 2;
  const int stc = (l & 3) ^ ((stl >> 1) & 3);
  const unsigned short* vsrc = vtp + stl * 1024 + j0 + (stc << 3);
#define STAGE(bf_, jb_)                                                        \
  {                                                                            \
    unsigned short* d_ = vts + (w << 12) + ((bf_) << 11);                      \
    const unsigned short* s_ = vsrc + (jb_);                                   \
    async_cp16(s_, d_);                                                        \
    async_cp16(s_ + 16384, d_ + 512);                                          \
    async_cp16(s_ + 32768, d_ + 1024);                                         \
    async_cp16(s_ + 49152, d_ + 1536);                                         \
  }
  STAGE(0, 0);
  float sq8[4];
#pragma unroll
  for (int t = 0; t < 4; ++t) sq8[t] = sqp[i0b + (rh << 6) + (t << 4) + lr];
  __syncthreads();

  f32x4 acc[4][4] = {};
  f32x4 accs[4] = {};
  short8 ones;
#pragma unroll
  for (int t = 0; t < 8; ++t) ones[t] = (short)0x3f80;  // bf16 1.0
  const int rx = (lr & 7) << 4;
  const int vread = (lc ^ ((lr >> 1) & 3)) << 3;

  int buf = 0;
  for (int s = 0; s < 16; ++s) {
    if (s < 15) {
      STAGE(buf ^ 1, (s + 1) << 5);
      asm volatile("s_waitcnt vmcnt(4)" ::: "memory");  // own slab(s) landed
    } else {
      asm volatile("s_waitcnt vmcnt(0)" ::: "memory");
    }
    __builtin_amdgcn_sched_barrier(0);
    const int jb = j0 + (s << 5);
    const int qb = (jb >> 3) + lc;
    const f32x4 s0 = *(const f32x4*)(sks + jb + (lc << 3));
    const f32x4 s1 = *(const f32x4*)(sks + jb + (lc << 3) + 4);
    U8 pa[4];
#pragma unroll
    for (int t = 0; t < 4; ++t) {
      const int row = (rh << 6) + (t << 4) + lr;
      const unsigned mb = (unsigned char)mks[(row << 7) + (qb ^ rx)];
      const float sqv = sq8[t];
      float e[8];
#pragma unroll
      for (int u = 0; u < 8; ++u) {
        float sv = sqv + (u < 4 ? s0[u] : s1[u - 4]);
        sv = fmaxf(sv, 0.2f * sv);  // leaky relu (log2e pre-folded)
        const float ex = __builtin_amdgcn_exp2f(sv);
        e[u] = (mb & (1u << u)) ? ex : 0.0f;
      }
      pa[t].u[0] = cvt_pk(e[0], e[1]); pa[t].u[1] = cvt_pk(e[2], e[3]);
      pa[t].u[2] = cvt_pk(e[4], e[5]); pa[t].u[3] = cvt_pk(e[6], e[7]);
    }
    const unsigned short* vbb = vts + (w << 12) + (buf << 11) + vread;
    __builtin_amdgcn_s_setprio(1);
#pragma unroll
    for (int c = 0; c < 4; ++c) {
      const short8 bv = *(const short8*)(vbb + ((c << 4) + lr) * 32);
#pragma unroll
      for (int t = 0; t < 4; ++t)
        acc[t][c] = __builtin_amdgcn_mfma_f32_16x16x32_bf16(pa[t].s, bv, acc[t][c], 0, 0, 0);
    }
#pragma unroll
    for (int t = 0; t < 4; ++t)
      accs[t] = __builtin_amdgcn_mfma_f32_16x16x32_bf16(pa[t].s, ones, accs[t], 0, 0, 0);
    __builtin_amdgcn_s_setprio(0);
    buf ^= 1;
  }
#undef STAGE

  // ---- 2-way j-half combine (cmb aliases dead slab memory)
  __syncthreads();
  float* cmb = (float*)smem;  // [2 rowhalf][64 lane][84] f32 = 43 KB
  if (jh == 1) {
    float* p = cmb + ((rh << 6) + l) * 84;
#pragma unroll
    for (int t = 0; t < 4; ++t) {
#pragma unroll
      for (int c = 0; c < 4; ++c) *(f32x4*)(p + (t * 4 + c) * 4) = acc[t][c];
      *(f32x4*)(p + 64 + t * 4) = accs[t];
    }
  }
  __syncthreads();
  if (jh == 0) {
    const float* p = cmb + ((rh << 6) + l) * 84;
#pragma unroll
    for (int t = 0; t < 4; ++t) {
#pragma unroll
      for (int c = 0; c < 4; ++c) {
        const f32x4 v = *(const f32x4*)(p + (t * 4 + c) * 4);
#pragma unroll
        for (int r = 0; r < 4; ++r) acc[t][c][r] += v[r];
      }
      const f32x4 vs = *(const f32x4*)(p + 64 + t * 4);
#pragma unroll
      for (int r = 0; r < 4; ++r) accs[t][r] += vs[r];
    }
#pragma unroll
    for (int t = 0; t < 4; ++t) {
#pragma unroll
      for (int r = 0; r < 4; ++r) {
        const float sv = accs[t][r];
        const float inv = sv > 0.0f ? 1.0f / sv : 0.0f;  // fully-masked row -> 0
        const int i = i0b + (rh << 6) + (t << 4) + (lc << 2) + r;
#pragma unroll
        for (int c = 0; c < 4; ++c)
          xb[(((size_t)(b * 1024 + i)) << 9) + h * 64 + (c << 4) + lr] =
              f2bf(acc[t][c][r] * inv);
      }
    }
  }
}

extern "C" void kernel_launch(void* const* d_in, const int* in_sizes, int n_in,
                              void* d_out, int out_size, void* d_ws, size_t ws_size,
                              hipStream_t stream) {
  const float* query = (const float*)d_in[0];
  const float* key   = (const float*)d_in[1];
  const float* value = (const float*)d_in[2];
  const int*   mask  = (const int*)d_in[3];
  const float* Wq = (const float*)d_in[4];
  const float* bq = (const float*)d_in[5];
  const float* Wk = (const float*)d_in[6];
  const float* bk = (const float*)d_in[7];
  const float* Wv = (const float*)d_in[8];
  const float* bv = (const float*)d_in[9];
  const float* Wo = (const float*)d_in[10];
  const float* bo = (const float*)d_in[11];
  const float* a  = (const float*)d_in[12];

  char* oc = (char*)d_out;
  unsigned short* vt = (unsigned short*)(oc + 0);
  unsigned int* mbits = (unsigned int*)(oc + 8388608);
  float* sqv = (float*)(oc + 9437184);
  float* skv = (float*)(oc + 9699328);
  unsigned short* Bfrag = (unsigned short*)(oc + 9961472);
  float* qkb = (float*)(oc + 9977856);
  unsigned short* wv16 = (unsigned short*)(oc + 10485760);
  unsigned short* xb = (unsigned short*)d_ws;

  const bool roomy = ws_size >= 8912896;
  unsigned short* wo16 = roomy ? (unsigned short*)((char*)d_ws + 8388608) : (unsigned short*)(oc + 11010048);

  prep_kernel<<<528, 256, 0, stream>>>(Wv, Wo, wv16, wo16, Wq, Wk, a, bq, bk, Bfrag, qkb);
  mid_kernel<<<9728, 256, 0, stream>>>(query, key, Bfrag, qkb, sqv, skv,
                                       value, wv16, bv, vt, mask, mbits);
  attn_kernel<<<512, 256, 0, stream>>>(sqv, skv, (const unsigned char*)mbits, vt, xb);
  if (roomy)
    gemm_bt<1><<<1024, 256, 0, stream>>>(xb, (const void*)wo16, bo, (float*)d_out);
  else
    gemm_bt<0><<<1024, 256, 0, stream>>>(xb, (const void*)Wo, bo, (float*)d_out);
}